// Round 14
// baseline (397.489 us; speedup 1.0000x reference)
//
#include <hip/hip_runtime.h>
#include <math.h>

// Problem constants
#define NB   8
#define CCH  256
#define PPX  2304            // 48*48
#define CPb  (CCH*PPX)       // per-batch C*P = 589824
#define NTOT (NB*CPb)        // 4718592
#define PSQ  (PPX*PPX)       // 5308416
#define PADIMG 2500          // 50*50 padded image

typedef short short8_t __attribute__((ext_vector_type(8)));
typedef float f4_t __attribute__((ext_vector_type(4)));

__device__ __forceinline__ float relu_(float x){ return x > 0.f ? x : 0.f; }

__device__ __forceinline__ unsigned short f2bf(float f) {
  unsigned int u = __builtin_bit_cast(unsigned int, f);
  u += 0x7fffu + ((u >> 16) & 1u);
  return (unsigned short)(u >> 16);
}
__device__ __forceinline__ float bf2f(unsigned short h) {
  unsigned int u = ((unsigned int)h) << 16;
  return __builtin_bit_cast(float, u);
}
__device__ __forceinline__ unsigned int pack2(float a, float b) {
  return (unsigned int)f2bf(a) | ((unsigned int)f2bf(b) << 16);
}

// async global -> LDS, 16B per lane, wave-uniform LDS base (lane spreads x16B)
__device__ __forceinline__ void gll16(const void* g, void* l) {
  __builtin_amdgcn_global_load_lds(
      (const __attribute__((address_space(1))) unsigned int*)g,
      (__attribute__((address_space(3))) unsigned int*)l, 16, 0, 0);
}

// ---------------------------------------------------------------------------
// small casts / repacks
// ---------------------------------------------------------------------------
__global__ __launch_bounds__(256) void castw(
    const float* __restrict__ w, unsigned short* __restrict__ o, int n)
{
  const int i = blockIdx.x * 256 + threadIdx.x;
  if (i < n) o[i] = f2bf(w[i]);
}

// concat bq||bk into one 512-float bias buffer
__global__ __launch_bounds__(256) void biascat(
    const float* __restrict__ a, const float* __restrict__ b,
    float* __restrict__ o)
{
  const int i = blockIdx.x * 256 + threadIdx.x;
  if (i < 256) o[i] = a[i];
  else if (i < 512) o[i] = b[i - 256];
}

// clear ONLY the 196 border positions of each padded [b][2500][C] image
__global__ __launch_bounds__(256) void border_clear(
    unsigned short* __restrict__ p, int C)
{
  const int idx = blockIdx.x * 256 + threadIdx.x;
  const int v4 = C >> 3;               // uint4 per border position
  const int perB = 196 * v4;
  if (idx >= NB * perB) return;
  const int b = idx / perB;
  const int r = idx - b * perB;
  const int pos = r / v4;
  const int co = (r - pos * v4) * 8;
  int pp;
  if (pos < 50)        pp = pos;                                   // row 0
  else if (pos < 100)  pp = 2450 + (pos - 50);                     // row 49
  else { const int j = pos - 100; pp = (1 + (j >> 1)) * 50 + (j & 1) * 49; }
  uint4 z; z.x = 0; z.y = 0; z.z = 0; z.w = 0;
  *(uint4*)(p + ((size_t)b * PADIMG + pp) * C + co) = z;
}

__global__ __launch_bounds__(256) void repack_w(
    const float* __restrict__ w, unsigned short* __restrict__ wr, int Cin)
{
  const int idx = blockIdx.x * 256 + threadIdx.x;
  const int total = 9 * 256 * Cin;
  if (idx >= total) return;
  const int c = idx % Cin;
  const int rest = idx / Cin;
  const int o = rest % 256;
  const int tap = rest / 256;
  wr[idx] = f2bf(w[((size_t)o * Cin + c) * 9 + tap]);
}

// ftr [b][c][p] fp32 -> x_t [b][p][c] bf16
__global__ __launch_bounds__(256) void transpose_cast(
    const float* __restrict__ ftr, unsigned short* __restrict__ xt)
{
  const int p0 = blockIdx.x * 64, c0 = blockIdx.y * 64, b = blockIdx.z;
  const int t = threadIdx.x;
  __shared__ unsigned short T[64][72];
  #pragma unroll
  for (int pass = 0; pass < 4; pass++) {
    const int cr = pass * 16 + (t >> 4);
    const int pc = (t & 15) * 4;
    float4 v = *(const float4*)&ftr[((size_t)(b * 256 + c0 + cr)) * PPX + p0 + pc];
    T[pc + 0][cr] = f2bf(v.x); T[pc + 1][cr] = f2bf(v.y);
    T[pc + 2][cr] = f2bf(v.z); T[pc + 3][cr] = f2bf(v.w);
  }
  __syncthreads();
  #pragma unroll
  for (int pass = 0; pass < 2; pass++) {
    const int pr = pass * 32 + (t >> 3);
    const int cc = (t & 7) * 8;
    *(uint4*)&xt[((size_t)(b * PPX + p0 + pr)) * 256 + c0 + cc] = *(const uint4*)&T[pr][cc];
  }
}

// ---------------------------------------------------------------------------
// Generic bf16 MFMA GEMM: O[n][m] = sum_k A[m][k]*B[n][k]
// Tile 128x128, 4 waves (2x2 of 64x64). Round-3 proven schedule.
// EPI: 2 bias on n (V gemm only)
// ---------------------------------------------------------------------------
template<int EPI>
__global__ __launch_bounds__(256) void gemm_nt(
    const unsigned short* __restrict__ A, long Ab,
    const unsigned short* __restrict__ B, long Bb, int K,
    unsigned short* __restrict__ O, long Ob, int ldo,
    const float* __restrict__ bias)
{
  const int t = threadIdx.x;
  const int ln = t & 63;
  const int wid = t >> 6;
  const int wm = (wid & 1) * 64, wn = (wid >> 1) * 64;
  const int lm = ln & 15, lg = ln >> 4;
  const int m0 = blockIdx.x * 128, n0 = blockIdx.y * 128;
  const long bz = blockIdx.z;
  const unsigned short* Ap = A + bz * Ab;
  const unsigned short* Bp = B + bz * Bb;

  __shared__ __align__(16) unsigned short As[128 * 32];
  __shared__ __align__(16) unsigned short Bs[128 * 32];

  const int sR = ln >> 2, sP = ln & 3;
  const int fbase = lm * 32 + (((lg + (lm >> 2)) & 3) * 8);

  f4_t acc[4][4];
  #pragma unroll
  for (int i = 0; i < 4; i++)
    #pragma unroll
    for (int j = 0; j < 4; j++) acc[i][j] = (f4_t){0.f, 0.f, 0.f, 0.f};

  for (int k0 = 0; k0 < K; k0 += 32) {
    __syncthreads();
    #pragma unroll
    for (int i = wid; i < 8; i += 4) {
      const int R = i * 16 + sR;
      const int l = (sP - (R >> 2)) & 3;              // logical chan-group
      gll16(Ap + (size_t)(m0 + R) * K + k0 + l * 8, As + i * 512);
      gll16(Bp + (size_t)(n0 + R) * K + k0 + l * 8, Bs + i * 512);
    }
    __syncthreads();
    short8_t a[4], b[4];
    #pragma unroll
    for (int ti = 0; ti < 4; ti++)
      a[ti] = *(const short8_t*)(As + (wm + ti * 16) * 32 + fbase);
    #pragma unroll
    for (int tj = 0; tj < 4; tj++)
      b[tj] = *(const short8_t*)(Bs + (wn + tj * 16) * 32 + fbase);
    #pragma unroll
    for (int ti = 0; ti < 4; ti++)
      #pragma unroll
      for (int tj = 0; tj < 4; tj++)
        acc[ti][tj] = __builtin_amdgcn_mfma_f32_16x16x32_bf16(
            a[ti], b[tj], acc[ti][tj], 0, 0, 0);
  }

  #pragma unroll
  for (int ti = 0; ti < 4; ti++) {
    const int mb = m0 + wm + ti * 16 + (lg << 2);
    #pragma unroll
    for (int tj = 0; tj < 4; tj++) {
      const int n = n0 + wn + tj * 16 + lm;
      float add0 = 0.f, add1 = 0.f, add2 = 0.f, add3 = 0.f;
      if (EPI == 2) { add0 = add1 = add2 = add3 = bias[n]; }
      uint2 o;
      o.x = pack2(acc[ti][tj][0] + add0, acc[ti][tj][1] + add1);
      o.y = pack2(acc[ti][tj][2] + add2, acc[ti][tj][3] + add3);
      *(uint2*)(O + bz * Ob + (size_t)n * ldo + mb) = o;
    }
  }
}

// ---------------------------------------------------------------------------
// QK^T GEMM, tile 128x128, BK=64: two 32-chan sub-slices staged per barrier,
// 32 MFMA per wave per iteration, 36 barriers. 32 KB LDS, acc 4x4.
// ---------------------------------------------------------------------------
__global__ __launch_bounds__(256) void gemm_s(
    const unsigned short* __restrict__ A, long Ab,
    const unsigned short* __restrict__ B, long Bb,
    unsigned short* __restrict__ O, long Ob, int ldo)
{
  const int K = 256;
  const int t = threadIdx.x;
  const int ln = t & 63;
  const int wid = t >> 6;
  const int wm = (wid & 1) * 64, wn = (wid >> 1) * 64;
  const int lm = ln & 15, lg = ln >> 4;
  const int m0 = blockIdx.x * 128, n0 = blockIdx.y * 128;
  const long bz = blockIdx.z;
  const unsigned short* Ap = A + bz * Ab;
  const unsigned short* Bp = B + bz * Bb;

  __shared__ __align__(16) unsigned short As[2][128 * 32];
  __shared__ __align__(16) unsigned short Bs[2][128 * 32];

  const int sR = ln >> 2, sP = ln & 3;
  const int fbase = lm * 32 + (((lg + (lm >> 2)) & 3) * 8);

  f4_t acc[4][4];
  #pragma unroll
  for (int i = 0; i < 4; i++)
    #pragma unroll
    for (int j = 0; j < 4; j++) acc[i][j] = (f4_t){0.f, 0.f, 0.f, 0.f};

  for (int k0 = 0; k0 < K; k0 += 64) {
    __syncthreads();
    #pragma unroll
    for (int s = 0; s < 2; s++) {
      #pragma unroll
      for (int i = wid; i < 8; i += 4) {
        const int R = i * 16 + sR;
        const int l = (sP - (R >> 2)) & 3;
        gll16(Ap + (size_t)(m0 + R) * K + k0 + s * 32 + l * 8, &As[s][i * 512]);
        gll16(Bp + (size_t)(n0 + R) * K + k0 + s * 32 + l * 8, &Bs[s][i * 512]);
      }
    }
    __syncthreads();
    #pragma unroll
    for (int s = 0; s < 2; s++) {
      short8_t a[4], b[4];
      #pragma unroll
      for (int ti = 0; ti < 4; ti++)
        a[ti] = *(const short8_t*)(&As[s][(wm + ti * 16) * 32 + fbase]);
      #pragma unroll
      for (int tj = 0; tj < 4; tj++)
        b[tj] = *(const short8_t*)(&Bs[s][(wn + tj * 16) * 32 + fbase]);
      #pragma unroll
      for (int ti = 0; ti < 4; ti++)
        #pragma unroll
        for (int tj = 0; tj < 4; tj++)
          acc[ti][tj] = __builtin_amdgcn_mfma_f32_16x16x32_bf16(
              a[ti], b[tj], acc[ti][tj], 0, 0, 0);
    }
  }

  #pragma unroll
  for (int ti = 0; ti < 4; ti++) {
    const int mb = m0 + wm + ti * 16 + (lg << 2);
    #pragma unroll
    for (int tj = 0; tj < 4; tj++) {
      const int n = n0 + wn + tj * 16 + lm;
      uint2 o;
      o.x = pack2(acc[ti][tj][0], acc[ti][tj][1]);
      o.y = pack2(acc[ti][tj][2], acc[ti][tj][3]);
      *(uint2*)(O + bz * Ob + (size_t)n * ldo + mb) = o;
    }
  }
}

// ---------------------------------------------------------------------------
// Merged Q+K GEMM (standalone clone of gemm_nt): A = wqb||wkb [512][256],
// B = xt. Rows 0..255 -> qt, 256..511 -> kt (= qt + NTOT).
// ---------------------------------------------------------------------------
__global__ __launch_bounds__(256) void gemm_qk2(
    const unsigned short* __restrict__ A,
    const unsigned short* __restrict__ B, long Bb,
    unsigned short* __restrict__ Oq,
    const float* __restrict__ bias)
{
  const int t = threadIdx.x;
  const int ln = t & 63;
  const int wid = t >> 6;
  const int wm = (wid & 1) * 64, wn = (wid >> 1) * 64;
  const int lm = ln & 15, lg = ln >> 4;
  const int m0 = blockIdx.x * 128, n0 = blockIdx.y * 128;
  const long bz = blockIdx.z;
  const int K = 256;
  const unsigned short* Ap = A;
  const unsigned short* Bp = B + bz * Bb;

  __shared__ __align__(16) unsigned short As[128 * 32];
  __shared__ __align__(16) unsigned short Bs[128 * 32];

  const int sR = ln >> 2, sP = ln & 3;
  const int fbase = lm * 32 + (((lg + (lm >> 2)) & 3) * 8);

  f4_t acc[4][4];
  #pragma unroll
  for (int i = 0; i < 4; i++)
    #pragma unroll
    for (int j = 0; j < 4; j++) acc[i][j] = (f4_t){0.f, 0.f, 0.f, 0.f};

  for (int k0 = 0; k0 < K; k0 += 32) {
    __syncthreads();
    #pragma unroll
    for (int i = wid; i < 8; i += 4) {
      const int R = i * 16 + sR;
      const int l = (sP - (R >> 2)) & 3;
      gll16(Ap + (size_t)(m0 + R) * K + k0 + l * 8, As + i * 512);
      gll16(Bp + (size_t)(n0 + R) * K + k0 + l * 8, Bs + i * 512);
    }
    __syncthreads();
    short8_t a[4], b[4];
    #pragma unroll
    for (int ti = 0; ti < 4; ti++)
      a[ti] = *(const short8_t*)(As + (wm + ti * 16) * 32 + fbase);
    #pragma unroll
    for (int tj = 0; tj < 4; tj++)
      b[tj] = *(const short8_t*)(Bs + (wn + tj * 16) * 32 + fbase);
    #pragma unroll
    for (int ti = 0; ti < 4; ti++)
      #pragma unroll
      for (int tj = 0; tj < 4; tj++)
        acc[ti][tj] = __builtin_amdgcn_mfma_f32_16x16x32_bf16(
            a[ti], b[tj], acc[ti][tj], 0, 0, 0);
  }

  #pragma unroll
  for (int ti = 0; ti < 4; ti++) {
    const int mb = m0 + wm + ti * 16 + (lg << 2);     // 0..511, wave-uniform split
    const size_t obase = (mb >= 256 ? (size_t)NTOT : 0) + (size_t)bz * CPb;
    const int mc = mb & 255;
    #pragma unroll
    for (int tj = 0; tj < 4; tj++) {
      const int n = n0 + wn + tj * 16 + lm;
      uint2 o;
      o.x = pack2(acc[ti][tj][0] + bias[mb],     acc[ti][tj][1] + bias[mb + 1]);
      o.y = pack2(acc[ti][tj][2] + bias[mb + 2], acc[ti][tj][3] + bias[mb + 3]);
      *(uint2*)(Oq + obase + (size_t)n * 256 + mc) = o;
    }
  }
}

// ---------------------------------------------------------------------------
// PV GEMM: tile 128(M=chan) x 32(N=pixel), 4 waves 2x2 (each 64x16, acc 4x1).
// Grid (2, 72, 8) = 1152 blocks = 4.5 blocks/CU = 18 waves/CU: occupancy is
// grid-limited (round-13 lesson) so double the blocks; St traffic unchanged
// (m-split stays 2), only L2-resident V gains re-reads. 10 KB LDS, BK=32.
// Epilogue: out = delta*acc + x (bf16 from xt, coalesced) -> attn_p [pos][256].
// ---------------------------------------------------------------------------
__global__ __launch_bounds__(256) void gemm_pv32(
    const unsigned short* __restrict__ A, long Ab,   // vbuf [c][i]
    const unsigned short* __restrict__ B, long Bb,   // St weights [j][i]
    int K,
    unsigned short* __restrict__ O,                  // attn_p
    const unsigned short* __restrict__ X,            // xt [b][p][c] bf16
    const float* __restrict__ delta, int bstart)
{
  const int t = threadIdx.x;
  const int ln = t & 63;
  const int wid = t >> 6;
  const int wm = (wid & 1) * 64, wn = (wid >> 1) * 16;
  const int lm = ln & 15, lg = ln >> 4;
  const int m0 = blockIdx.x * 128, n0 = blockIdx.y * 32;
  const long bz = blockIdx.z;
  const int b = bstart + (int)bz;
  const unsigned short* Ap = A + bz * Ab;
  const unsigned short* Bp = B + bz * Bb;

  __shared__ __align__(16) unsigned short As[128 * 32];
  __shared__ __align__(16) unsigned short Bs[32 * 32];

  const int sR = ln >> 2, sP = ln & 3;
  const int fbase = lm * 32 + (((lg + (lm >> 2)) & 3) * 8);

  f4_t acc[4];
  #pragma unroll
  for (int i = 0; i < 4; i++) acc[i] = (f4_t){0.f, 0.f, 0.f, 0.f};

  for (int k0 = 0; k0 < K; k0 += 32) {
    __syncthreads();
    #pragma unroll
    for (int i = wid; i < 8; i += 4) {
      const int R = i * 16 + sR;
      const int l = (sP - (R >> 2)) & 3;
      gll16(Ap + (size_t)(m0 + R) * K + k0 + l * 8, As + i * 512);
    }
    if (wid < 2) {
      const int R = wid * 16 + sR;                    // rows 0..31, 2 chunks
      const int l = (sP - (R >> 2)) & 3;
      gll16(Bp + (size_t)(n0 + R) * K + k0 + l * 8, Bs + wid * 512);
    }
    __syncthreads();
    short8_t a[4], b8;
    #pragma unroll
    for (int ti = 0; ti < 4; ti++)
      a[ti] = *(const short8_t*)(As + (wm + ti * 16) * 32 + fbase);
    b8 = *(const short8_t*)(Bs + wn * 32 + fbase);
    #pragma unroll
    for (int ti = 0; ti < 4; ti++)
      acc[ti] = __builtin_amdgcn_mfma_f32_16x16x32_bf16(
          a[ti], b8, acc[ti], 0, 0, 0);
  }

  const float d0 = delta[0];
  const int n = n0 + wn + lm;                          // pixel j
  const int y = n / 48, x = n - (n / 48) * 48;
  const size_t pp = (size_t)(y + 1) * 50 + (x + 1);
  #pragma unroll
  for (int ti = 0; ti < 4; ti++) {
    const int mb = m0 + wm + ti * 16 + (lg << 2);     // channel c
    const uint2 xv = *(const uint2*)(X + ((size_t)b * PPX + n) * 256 + mb);
    float fr[4];
    fr[0] = bf2f((unsigned short)(xv.x & 0xffffu));
    fr[1] = bf2f((unsigned short)(xv.x >> 16));
    fr[2] = bf2f((unsigned short)(xv.y & 0xffffu));
    fr[3] = bf2f((unsigned short)(xv.y >> 16));
    float vr[4];
    #pragma unroll
    for (int r = 0; r < 4; r++)
      vr[r] = d0 * acc[ti][r] + fr[r];
    uint2 o;
    o.x = pack2(vr[0], vr[1]);
    o.y = pack2(vr[2], vr[3]);
    *(uint2*)(O + ((size_t)b * PADIMG + pp) * 256 + mb) = o;
  }
}

// ---------------------------------------------------------------------------
// Row softmax of St IN PLACE: row j: W[i] = exp(s-mx)/sum  (bf16 out)
// ---------------------------------------------------------------------------
__global__ __launch_bounds__(256) void rowstats(
    unsigned short* __restrict__ St, long sstride)
{
  const int j = blockIdx.x, bb = blockIdx.y;
  unsigned short* row = St + (long)bb * sstride + (size_t)j * PPX;
  const int t = threadIdx.x;

  float v[16];
  int nv = 0;
  float m = -1e30f;
  for (int ch = t; ch < 288; ch += 256) {
    const uint4 d = *(const uint4*)(row + ch * 8);
    const unsigned int* dp = (const unsigned int*)&d;
    #pragma unroll
    for (int q = 0; q < 4; q++) {
      v[nv]     = bf2f((unsigned short)(dp[q] & 0xffffu));
      v[nv + 1] = bf2f((unsigned short)(dp[q] >> 16));
      m = fmaxf(m, fmaxf(v[nv], v[nv + 1]));
      nv += 2;
    }
  }
  #pragma unroll
  for (int off = 32; off > 0; off >>= 1)
    m = fmaxf(m, __shfl_xor(m, off));
  __shared__ float red[8];
  if ((t & 63) == 0) red[t >> 6] = m;
  __syncthreads();
  m = fmaxf(fmaxf(red[0], red[1]), fmaxf(red[2], red[3]));

  float sum = 0.f;
  for (int u = 0; u < nv; u++) { v[u] = __expf(v[u] - m); sum += v[u]; }
  #pragma unroll
  for (int off = 32; off > 0; off >>= 1)
    sum += __shfl_xor(sum, off);
  if ((t & 63) == 0) red[4 + (t >> 6)] = sum;
  __syncthreads();
  const float inv = 1.f / (red[4] + red[5] + red[6] + red[7]);

  int u = 0;
  for (int ch = t; ch < 288; ch += 256) {
    unsigned int res[4];
    #pragma unroll
    for (int q = 0; q < 4; q++) {
      res[q] = pack2(v[u] * inv, v[u + 1] * inv);
      u += 2;
    }
    *(uint4*)(row + ch * 8) = *(const uint4*)res;
  }
}

// ---------------------------------------------------------------------------
// Conv3x3 + BN + ReLU, MFMA bf16, [pos][chan] activations, async LDS staging.
// 256 thr (4 waves), tile 32 Cout x 192 px. Grid = 768 blocks = 3/CU.
// ---------------------------------------------------------------------------
template<bool OUT_BF16>
__global__ __launch_bounds__(256) void conv_mfma(
    const unsigned short* __restrict__ act_p, int Cin,
    const unsigned short* __restrict__ wr,
    const float* __restrict__ gamma, const float* __restrict__ beta,
    const float* __restrict__ mean,  const float* __restrict__ var,
    void* __restrict__ outv)
{
  const int t  = threadIdx.x;
  const int wv = t >> 6;          // wave 0..3 -> 48-px chunk
  const int ln = t & 63;
  const int lm = ln & 15;
  const int lg = ln >> 4;

  const int bx = blockIdx.x;      // 96 = 8 images * 12 pixel-tiles (192 px)
  const int bb = bx / 12;
  const int p0 = (bx % 12) * 192;
  const int m0 = blockIdx.y * 32; // 8 m-tiles of 32 Cout

  __shared__ __align__(16) unsigned short As[9 * 32 * 32]; // [tap][m][c] 18.4 KB
  __shared__ __align__(16) unsigned short Bs[304 * 32];    // [pos][c]    19.5 KB

  const int qbase = p0 + 2 * (p0 / 48);    // q(p0) - 51
  int qoff[3];
  #pragma unroll
  for (int tj = 0; tj < 3; tj++) {
    const int p = p0 + wv * 48 + tj * 16 + lm;
    qoff[tj] = (p - p0) + 2 * (p / 48 - p0 / 48) + 51;
  }

  const int sR = ln >> 2, sP = ln & 3;
  const int sl = (sP - (sR >> 2)) & 3;
  const int abase = lm * 32 + (((lg + (lm >> 2)) & 3) * 8);

  const unsigned short* gb = act_p + (size_t)bb * PADIMG * Cin + sl * 8;

  f4_t acc[2][3];
  #pragma unroll
  for (int i = 0; i < 2; i++)
    #pragma unroll
    for (int j = 0; j < 3; j++) acc[i][j] = (f4_t){0.f, 0.f, 0.f, 0.f};

  for (int c0 = 0; c0 < Cin; c0 += 32) {
    __syncthreads();
    for (int i = wv; i < 18; i += 4) {
      const int R = i * 16 + sR;                          // 0..287
      const int tap = R >> 5, mr = R & 31;
      const int l = (sP - (R >> 2)) & 3;
      gll16(wr + ((size_t)(tap * 256 + m0 + mr)) * Cin + c0 + l * 8, As + i * 512);
    }
    for (int i = wv; i < 19; i += 4) {
      const int R = i * 16 + sR;                          // 0..303
      int Rg = qbase + R;
      if (Rg > PADIMG - 1) Rg = PADIMG - 1;
      gll16(gb + (size_t)Rg * Cin + c0, Bs + i * 512);
    }
    __syncthreads();
    #pragma unroll
    for (int ky = 0; ky < 3; ky++) {
      #pragma unroll
      for (int kx = 0; kx < 3; kx++) {
        const int off = (ky - 1) * 50 + (kx - 1);
        const int tap = ky * 3 + kx;
        short8_t a[2], b[3];
        #pragma unroll
        for (int ti = 0; ti < 2; ti++)
          a[ti] = *(const short8_t*)(As + tap * 1024 + ti * 512 + abase);
        #pragma unroll
        for (int tj = 0; tj < 3; tj++) {
          const int R = qoff[tj] + off;
          const int slot = (lg + (R >> 2)) & 3;
          b[tj] = *(const short8_t*)(Bs + R * 32 + slot * 8);
        }
        #pragma unroll
        for (int ti = 0; ti < 2; ti++)
          #pragma unroll
          for (int tj = 0; tj < 3; tj++)
            acc[ti][tj] = __builtin_amdgcn_mfma_f32_16x16x32_bf16(
                a[ti], b[tj], acc[ti][tj], 0, 0, 0);
      }
    }
  }

  // ---- epilogue: BN + ReLU ----
  #pragma unroll
  for (int ti = 0; ti < 2; ti++) {
    const int m = m0 + ti * 16 + (lg << 2);
    float inv[4], add[4];
    #pragma unroll
    for (int r = 0; r < 4; r++) {
      inv[r] = gamma[m + r] * rsqrtf(var[m + r] + 1e-5f);
      add[r] = beta[m + r] - mean[m + r] * inv[r];
    }
    #pragma unroll
    for (int tj = 0; tj < 3; tj++) {
      const int p = p0 + wv * 48 + tj * 16 + lm;
      float vr[4];
      #pragma unroll
      for (int r = 0; r < 4; r++)
        vr[r] = relu_(acc[ti][tj][r] * inv[r] + add[r]);
      if (OUT_BF16) {
        uint2 o;
        o.x = pack2(vr[0], vr[1]);
        o.y = pack2(vr[2], vr[3]);
        *(uint2*)((unsigned short*)outv + ((size_t)(bb * PPX + p)) * 256 + m) = o;
      } else {
        #pragma unroll
        for (int r = 0; r < 4; r++)
          ((float*)outv)[((size_t)(bb * 256 + m + r)) * PPX + p] = vr[r];
      }
    }
  }
}

// ---------------------------------------------------------------------------
// pool3(avg/max of xt bf16) * sigmoid(act1) -> padded bf16 cat [pos][512]
// Vectorized: 8 channels per thread (uint4 loads/stores).
// ---------------------------------------------------------------------------
__global__ __launch_bounds__(256) void pool_gate_cat(
    const unsigned short* __restrict__ xt, const unsigned short* __restrict__ act1b,
    unsigned short* __restrict__ cat_p)
{
  const int idx = blockIdx.x * 256 + threadIdx.x;   // < NTOT/8
  const int cg = (idx & 31) * 8;
  const int rest = idx >> 5;
  const int p = rest % PPX;
  const int b = rest / PPX;
  const int y = p / 48, x = p - y * 48;
  const unsigned short* base = xt + ((size_t)b * PPX) * 256 + cg;
  float s[8], mx[8];
  #pragma unroll
  for (int e = 0; e < 8; e++) { s[e] = 0.f; mx[e] = -1e30f; }
  #pragma unroll
  for (int dy = -1; dy <= 1; dy++) {
    const int yy = y + dy;
    if (yy < 0 || yy >= 48) continue;
    #pragma unroll
    for (int dx = -1; dx <= 1; dx++) {
      const int xx = x + dx;
      if (xx < 0 || xx >= 48) continue;
      const uint4 d = *(const uint4*)&base[(size_t)(yy * 48 + xx) * 256];
      const unsigned int* dp = (const unsigned int*)&d;
      #pragma unroll
      for (int q = 0; q < 4; q++) {
        const float f0 = bf2f((unsigned short)(dp[q] & 0xffffu));
        const float f1 = bf2f((unsigned short)(dp[q] >> 16));
        s[2 * q] += f0; s[2 * q + 1] += f1;
        mx[2 * q] = fmaxf(mx[2 * q], f0);
        mx[2 * q + 1] = fmaxf(mx[2 * q + 1], f1);
      }
    }
  }
  const uint4 g4 = *(const uint4*)&act1b[((size_t)b * PPX + p) * 256 + cg];
  const unsigned int* gp = (const unsigned int*)&g4;
  unsigned int om[4], oa[4];
  #pragma unroll
  for (int q = 0; q < 4; q++) {
    const float g0 = bf2f((unsigned short)(gp[q] & 0xffffu));
    const float g1 = bf2f((unsigned short)(gp[q] >> 16));
    const float gt0 = 1.f / (1.f + __expf(-g0));
    const float gt1 = 1.f / (1.f + __expf(-g1));
    om[q] = pack2(mx[2 * q] * gt0, mx[2 * q + 1] * gt1);
    oa[q] = pack2(s[2 * q] * (1.f / 9.f) * gt0, s[2 * q + 1] * (1.f / 9.f) * gt1);
  }
  const size_t pp = (size_t)(y + 1) * 50 + (x + 1);
  unsigned short* crow = cat_p + ((size_t)b * PADIMG + pp) * 512 + cg;
  *(uint4*)crow = *(const uint4*)om;
  *(uint4*)(crow + 256) = *(const uint4*)oa;
}

// ---------------------------------------------------------------------------
extern "C" void kernel_launch(void* const* d_in, const int* in_sizes, int n_in,
                              void* d_out, int out_size, void* d_ws, size_t ws_size,
                              hipStream_t stream)
{
  const float* ftr  = (const float*)d_in[0];
  const float* wq   = (const float*)d_in[1];
  const float* bq   = (const float*)d_in[2];
  const float* wk   = (const float*)d_in[3];
  const float* bk   = (const float*)d_in[4];
  const float* wv   = (const float*)d_in[5];
  const float* bv   = (const float*)d_in[6];
  const float* delta= (const float*)d_in[7];
  const float* w1   = (const float*)d_in[8];
  const float* g1   = (const float*)d_in[9];
  const float* b1   = (const float*)d_in[10];
  const float* m1   = (const float*)d_in[11];
  const float* v1   = (const float*)d_in[12];
  const float* w2   = (const float*)d_in[13];
  const float* g2   = (const float*)d_in[14];
  const float* b2   = (const float*)d_in[15];
  const float* m2   = (const float*)d_in[16];
  const float* v2   = (const float*)d_in[17];
  float* out = (float*)d_out;

  // ---- workspace layout (shorts) ----
  const size_t XT = (size_t)NTOT;
  unsigned short* base = (unsigned short*)d_ws;
  unsigned short* xt   = base;
  unsigned short* qt   = xt  + XT;
  unsigned short* kt   = qt  + XT;        // MUST stay qt + NTOT (gemm_qk2 relies on it)
  unsigned short* vbuf = kt  + XT;
  unsigned short* wqb  = vbuf + XT;
  unsigned short* wkb  = wqb + 65536;     // MUST stay wqb + 65536 (contiguous A)
  unsigned short* wvb  = wkb + 65536;
  unsigned short* wr1  = wvb + 65536;
  unsigned short* wr2  = wr1 + (size_t)9 * 256 * 256;
  unsigned short* attn_p = wr2 + (size_t)9 * 256 * 512;        // [b][2500][256]
  unsigned short* act1b  = attn_p + (size_t)NB * PADIMG * 256; // [b][2304][256]
  unsigned short* cat_p  = act1b + XT;                         // [b][2500][512]
  unsigned short* St     = cat_p + (size_t)NB * PADIMG * 512;

  // bqk (512 floats) overlays act1b (unused until conv1)
  float* bqk = (float*)act1b;

  const size_t head_bytes = (size_t)((char*)St - (char*)base);
  const bool modeA = ws_size >= head_bytes + (size_t)NB * PSQ * 2;

  // ---- weight preps ----
  castw<<<dim3(256), 256, 0, stream>>>(wq, wqb, 65536);
  castw<<<dim3(256), 256, 0, stream>>>(wk, wkb, 65536);
  castw<<<dim3(256), 256, 0, stream>>>(wv, wvb, 65536);
  biascat<<<dim3(2), 256, 0, stream>>>(bq, bk, bqk);
  repack_w<<<dim3((9 * 256 * 256 + 255) / 256), 256, 0, stream>>>(w1, wr1, 256);
  repack_w<<<dim3((9 * 256 * 512 + 255) / 256), 256, 0, stream>>>(w2, wr2, 512);

  // ---- x transpose ----
  transpose_cast<<<dim3(36, 4, 8), 256, 0, stream>>>(ftr, xt);

  // ---- QKV: merged Q+K (576 blocks), V separate ----
  gemm_qk2<<<dim3(4, 18, 8), 256, 0, stream>>>(wqb, xt, (long)CPb, qt, bqk);
  gemm_nt<2><<<dim3(18, 2, 8), 256, 0, stream>>>(
      xt, (long)CPb, wvb, 0L, 256, vbuf, (long)CPb, PPX, bv);

  // ---- clear ONLY attn_p borders (interior fully overwritten by PV) ----
  border_clear<<<dim3(196), 256, 0, stream>>>(attn_p, 256);

  if (modeA) {
    gemm_s<<<dim3(18, 18, 8), 256, 0, stream>>>(
        qt, (long)CPb, kt, (long)CPb, St, (long)PSQ, PPX);
    rowstats<<<dim3(PPX, 8), 256, 0, stream>>>(St, (long)PSQ);
    gemm_pv32<<<dim3(2, 72, 8), 256, 0, stream>>>(
        vbuf, (long)CPb, St, (long)PSQ, PPX, attn_p, xt, delta, 0);
  } else {
    for (int b = 0; b < NB; b++) {
      gemm_s<<<dim3(18, 18, 1), 256, 0, stream>>>(
          qt + (size_t)b * CPb, 0L, kt + (size_t)b * CPb, 0L, St, 0L, PPX);
      rowstats<<<dim3(PPX, 1), 256, 0, stream>>>(St, 0L);
      gemm_pv32<<<dim3(2, 72, 1), 256, 0, stream>>>(
          vbuf + (size_t)b * CPb, 0L, St, 0L, PPX, attn_p, xt, delta, b);
    }
  }

  // ---- conv1 + BN + ReLU -> bf16 act1b [p][c] ----
  conv_mfma<true><<<dim3(96, 8), 256, 0, stream>>>(
      attn_p, 256, wr1, g1, b1, m1, v1, (void*)act1b);

  // ---- clear ONLY cat_p borders, then pool + gate + concat ----
  border_clear<<<dim3(392), 256, 0, stream>>>(cat_p, 512);
  pool_gate_cat<<<dim3(NTOT / 8 / 256), 256, 0, stream>>>(xt, act1b, cat_p);

  // ---- conv2 + BN + ReLU -> fp32 out ----
  conv_mfma<false><<<dim3(96, 8), 256, 0, stream>>>(
      cat_p, 512, wr2, g2, b2, m2, v2, (void*)out);
}

// Round 15
// 380.047 us; speedup vs baseline: 1.0459x; 1.0459x over previous
//
#include <hip/hip_runtime.h>
#include <math.h>

// Problem constants
#define NB   8
#define CCH  256
#define PPX  2304            // 48*48
#define CPb  (CCH*PPX)       // per-batch C*P = 589824
#define NTOT (NB*CPb)        // 4718592
#define PSQ  (PPX*PPX)       // 5308416
#define PADIMG 2500          // 50*50 padded image

typedef short short8_t __attribute__((ext_vector_type(8)));
typedef float f4_t __attribute__((ext_vector_type(4)));

__device__ __forceinline__ float relu_(float x){ return x > 0.f ? x : 0.f; }

__device__ __forceinline__ unsigned short f2bf(float f) {
  unsigned int u = __builtin_bit_cast(unsigned int, f);
  u += 0x7fffu + ((u >> 16) & 1u);
  return (unsigned short)(u >> 16);
}
__device__ __forceinline__ float bf2f(unsigned short h) {
  unsigned int u = ((unsigned int)h) << 16;
  return __builtin_bit_cast(float, u);
}
__device__ __forceinline__ unsigned int pack2(float a, float b) {
  return (unsigned int)f2bf(a) | ((unsigned int)f2bf(b) << 16);
}

// async global -> LDS, 16B per lane, wave-uniform LDS base (lane spreads x16B)
__device__ __forceinline__ void gll16(const void* g, void* l) {
  __builtin_amdgcn_global_load_lds(
      (const __attribute__((address_space(1))) unsigned int*)g,
      (__attribute__((address_space(3))) unsigned int*)l, 16, 0, 0);
}

// XCD-aware chunked block swizzle (T1): consecutive LOGICAL blocks land on
// the same XCD's L2. Bijective when total%8==0, else identity (ERRATA #11).
__device__ __forceinline__ int swz_lin() {
  const int L = (int)(blockIdx.x + gridDim.x * (blockIdx.y + gridDim.y * blockIdx.z));
  const int total = (int)(gridDim.x * gridDim.y * gridDim.z);
  if ((total & 7) == 0) {
    const int q = total >> 3;
    return (L & 7) * q + (L >> 3);
  }
  return L;
}

// ---------------------------------------------------------------------------
// small casts / repacks
// ---------------------------------------------------------------------------
__global__ __launch_bounds__(256) void castw(
    const float* __restrict__ w, unsigned short* __restrict__ o, int n)
{
  const int i = blockIdx.x * 256 + threadIdx.x;
  if (i < n) o[i] = f2bf(w[i]);
}

// concat bq||bk into one 512-float bias buffer
__global__ __launch_bounds__(256) void biascat(
    const float* __restrict__ a, const float* __restrict__ b,
    float* __restrict__ o)
{
  const int i = blockIdx.x * 256 + threadIdx.x;
  if (i < 256) o[i] = a[i];
  else if (i < 512) o[i] = b[i - 256];
}

// clear ONLY the 196 border positions of each padded [b][2500][C] image
__global__ __launch_bounds__(256) void border_clear(
    unsigned short* __restrict__ p, int C)
{
  const int idx = blockIdx.x * 256 + threadIdx.x;
  const int v4 = C >> 3;               // uint4 per border position
  const int perB = 196 * v4;
  if (idx >= NB * perB) return;
  const int b = idx / perB;
  const int r = idx - b * perB;
  const int pos = r / v4;
  const int co = (r - pos * v4) * 8;
  int pp;
  if (pos < 50)        pp = pos;                                   // row 0
  else if (pos < 100)  pp = 2450 + (pos - 50);                     // row 49
  else { const int j = pos - 100; pp = (1 + (j >> 1)) * 50 + (j & 1) * 49; }
  uint4 z; z.x = 0; z.y = 0; z.z = 0; z.w = 0;
  *(uint4*)(p + ((size_t)b * PADIMG + pp) * C + co) = z;
}

__global__ __launch_bounds__(256) void repack_w(
    const float* __restrict__ w, unsigned short* __restrict__ wr, int Cin)
{
  const int idx = blockIdx.x * 256 + threadIdx.x;
  const int total = 9 * 256 * Cin;
  if (idx >= total) return;
  const int c = idx % Cin;
  const int rest = idx / Cin;
  const int o = rest % 256;
  const int tap = rest / 256;
  wr[idx] = f2bf(w[((size_t)o * Cin + c) * 9 + tap]);
}

// ftr [b][c][p] fp32 -> x_t [b][p][c] bf16
__global__ __launch_bounds__(256) void transpose_cast(
    const float* __restrict__ ftr, unsigned short* __restrict__ xt)
{
  const int p0 = blockIdx.x * 64, c0 = blockIdx.y * 64, b = blockIdx.z;
  const int t = threadIdx.x;
  __shared__ unsigned short T[64][72];
  #pragma unroll
  for (int pass = 0; pass < 4; pass++) {
    const int cr = pass * 16 + (t >> 4);
    const int pc = (t & 15) * 4;
    float4 v = *(const float4*)&ftr[((size_t)(b * 256 + c0 + cr)) * PPX + p0 + pc];
    T[pc + 0][cr] = f2bf(v.x); T[pc + 1][cr] = f2bf(v.y);
    T[pc + 2][cr] = f2bf(v.z); T[pc + 3][cr] = f2bf(v.w);
  }
  __syncthreads();
  #pragma unroll
  for (int pass = 0; pass < 2; pass++) {
    const int pr = pass * 32 + (t >> 3);
    const int cc = (t & 7) * 8;
    *(uint4*)&xt[((size_t)(b * PPX + p0 + pr)) * 256 + c0 + cc] = *(const uint4*)&T[pr][cc];
  }
}

// ---------------------------------------------------------------------------
// Generic bf16 MFMA GEMM: O[n][m] = sum_k A[m][k]*B[n][k]
// Tile 128x128, 4 waves (2x2 of 64x64). Round-3 proven schedule.
// EPI: 2 bias on n (V gemm only)
// ---------------------------------------------------------------------------
template<int EPI>
__global__ __launch_bounds__(256) void gemm_nt(
    const unsigned short* __restrict__ A, long Ab,
    const unsigned short* __restrict__ B, long Bb, int K,
    unsigned short* __restrict__ O, long Ob, int ldo,
    const float* __restrict__ bias)
{
  const int t = threadIdx.x;
  const int ln = t & 63;
  const int wid = t >> 6;
  const int wm = (wid & 1) * 64, wn = (wid >> 1) * 64;
  const int lm = ln & 15, lg = ln >> 4;
  const int m0 = blockIdx.x * 128, n0 = blockIdx.y * 128;
  const long bz = blockIdx.z;
  const unsigned short* Ap = A + bz * Ab;
  const unsigned short* Bp = B + bz * Bb;

  __shared__ __align__(16) unsigned short As[128 * 32];
  __shared__ __align__(16) unsigned short Bs[128 * 32];

  const int sR = ln >> 2, sP = ln & 3;
  const int fbase = lm * 32 + (((lg + (lm >> 2)) & 3) * 8);

  f4_t acc[4][4];
  #pragma unroll
  for (int i = 0; i < 4; i++)
    #pragma unroll
    for (int j = 0; j < 4; j++) acc[i][j] = (f4_t){0.f, 0.f, 0.f, 0.f};

  for (int k0 = 0; k0 < K; k0 += 32) {
    __syncthreads();
    #pragma unroll
    for (int i = wid; i < 8; i += 4) {
      const int R = i * 16 + sR;
      const int l = (sP - (R >> 2)) & 3;              // logical chan-group
      gll16(Ap + (size_t)(m0 + R) * K + k0 + l * 8, As + i * 512);
      gll16(Bp + (size_t)(n0 + R) * K + k0 + l * 8, Bs + i * 512);
    }
    __syncthreads();
    short8_t a[4], b[4];
    #pragma unroll
    for (int ti = 0; ti < 4; ti++)
      a[ti] = *(const short8_t*)(As + (wm + ti * 16) * 32 + fbase);
    #pragma unroll
    for (int tj = 0; tj < 4; tj++)
      b[tj] = *(const short8_t*)(Bs + (wn + tj * 16) * 32 + fbase);
    #pragma unroll
    for (int ti = 0; ti < 4; ti++)
      #pragma unroll
      for (int tj = 0; tj < 4; tj++)
        acc[ti][tj] = __builtin_amdgcn_mfma_f32_16x16x32_bf16(
            a[ti], b[tj], acc[ti][tj], 0, 0, 0);
  }

  #pragma unroll
  for (int ti = 0; ti < 4; ti++) {
    const int mb = m0 + wm + ti * 16 + (lg << 2);
    #pragma unroll
    for (int tj = 0; tj < 4; tj++) {
      const int n = n0 + wn + tj * 16 + lm;
      float add0 = 0.f, add1 = 0.f, add2 = 0.f, add3 = 0.f;
      if (EPI == 2) { add0 = add1 = add2 = add3 = bias[n]; }
      uint2 o;
      o.x = pack2(acc[ti][tj][0] + add0, acc[ti][tj][1] + add1);
      o.y = pack2(acc[ti][tj][2] + add2, acc[ti][tj][3] + add3);
      *(uint2*)(O + bz * Ob + (size_t)n * ldo + mb) = o;
    }
  }
}

// ---------------------------------------------------------------------------
// QK^T GEMM, tile 128x128, BK=64: two 32-chan sub-slices staged per barrier,
// 32 MFMA per wave per iteration, 36 barriers. 32 KB LDS, acc 4x4.
// XCD-swizzled block order: x-neighbors (sharing the kt B-panel) co-locate
// on one XCD's L2.
// ---------------------------------------------------------------------------
__global__ __launch_bounds__(256) void gemm_s(
    const unsigned short* __restrict__ A, long Ab,
    const unsigned short* __restrict__ B, long Bb,
    unsigned short* __restrict__ O, long Ob, int ldo)
{
  const int K = 256;
  const int t = threadIdx.x;
  const int ln = t & 63;
  const int wid = t >> 6;
  const int wm = (wid & 1) * 64, wn = (wid >> 1) * 64;
  const int lm = ln & 15, lg = ln >> 4;

  const int lin = swz_lin();
  const int lx = lin % (int)gridDim.x;
  const int rest = lin / (int)gridDim.x;
  const int ly = rest % (int)gridDim.y;
  const int lz = rest / (int)gridDim.y;

  const int m0 = lx * 128, n0 = ly * 128;
  const long bz = lz;
  const unsigned short* Ap = A + bz * Ab;
  const unsigned short* Bp = B + bz * Bb;

  __shared__ __align__(16) unsigned short As[2][128 * 32];
  __shared__ __align__(16) unsigned short Bs[2][128 * 32];

  const int sR = ln >> 2, sP = ln & 3;
  const int fbase = lm * 32 + (((lg + (lm >> 2)) & 3) * 8);

  f4_t acc[4][4];
  #pragma unroll
  for (int i = 0; i < 4; i++)
    #pragma unroll
    for (int j = 0; j < 4; j++) acc[i][j] = (f4_t){0.f, 0.f, 0.f, 0.f};

  for (int k0 = 0; k0 < K; k0 += 64) {
    __syncthreads();
    #pragma unroll
    for (int s = 0; s < 2; s++) {
      #pragma unroll
      for (int i = wid; i < 8; i += 4) {
        const int R = i * 16 + sR;
        const int l = (sP - (R >> 2)) & 3;
        gll16(Ap + (size_t)(m0 + R) * K + k0 + s * 32 + l * 8, &As[s][i * 512]);
        gll16(Bp + (size_t)(n0 + R) * K + k0 + s * 32 + l * 8, &Bs[s][i * 512]);
      }
    }
    __syncthreads();
    #pragma unroll
    for (int s = 0; s < 2; s++) {
      short8_t a[4], b[4];
      #pragma unroll
      for (int ti = 0; ti < 4; ti++)
        a[ti] = *(const short8_t*)(&As[s][(wm + ti * 16) * 32 + fbase]);
      #pragma unroll
      for (int tj = 0; tj < 4; tj++)
        b[tj] = *(const short8_t*)(&Bs[s][(wn + tj * 16) * 32 + fbase]);
      #pragma unroll
      for (int ti = 0; ti < 4; ti++)
        #pragma unroll
        for (int tj = 0; tj < 4; tj++)
          acc[ti][tj] = __builtin_amdgcn_mfma_f32_16x16x32_bf16(
              a[ti], b[tj], acc[ti][tj], 0, 0, 0);
    }
  }

  #pragma unroll
  for (int ti = 0; ti < 4; ti++) {
    const int mb = m0 + wm + ti * 16 + (lg << 2);
    #pragma unroll
    for (int tj = 0; tj < 4; tj++) {
      const int n = n0 + wn + tj * 16 + lm;
      uint2 o;
      o.x = pack2(acc[ti][tj][0], acc[ti][tj][1]);
      o.y = pack2(acc[ti][tj][2], acc[ti][tj][3]);
      *(uint2*)(O + bz * Ob + (size_t)n * ldo + mb) = o;
    }
  }
}

// ---------------------------------------------------------------------------
// Merged Q+K GEMM (standalone clone of gemm_nt): A = wqb||wkb [512][256],
// B = xt. Rows 0..255 -> qt, 256..511 -> kt (= qt + NTOT).
// ---------------------------------------------------------------------------
__global__ __launch_bounds__(256) void gemm_qk2(
    const unsigned short* __restrict__ A,
    const unsigned short* __restrict__ B, long Bb,
    unsigned short* __restrict__ Oq,
    const float* __restrict__ bias)
{
  const int t = threadIdx.x;
  const int ln = t & 63;
  const int wid = t >> 6;
  const int wm = (wid & 1) * 64, wn = (wid >> 1) * 64;
  const int lm = ln & 15, lg = ln >> 4;
  const int m0 = blockIdx.x * 128, n0 = blockIdx.y * 128;
  const long bz = blockIdx.z;
  const int K = 256;
  const unsigned short* Ap = A;
  const unsigned short* Bp = B + bz * Bb;

  __shared__ __align__(16) unsigned short As[128 * 32];
  __shared__ __align__(16) unsigned short Bs[128 * 32];

  const int sR = ln >> 2, sP = ln & 3;
  const int fbase = lm * 32 + (((lg + (lm >> 2)) & 3) * 8);

  f4_t acc[4][4];
  #pragma unroll
  for (int i = 0; i < 4; i++)
    #pragma unroll
    for (int j = 0; j < 4; j++) acc[i][j] = (f4_t){0.f, 0.f, 0.f, 0.f};

  for (int k0 = 0; k0 < K; k0 += 32) {
    __syncthreads();
    #pragma unroll
    for (int i = wid; i < 8; i += 4) {
      const int R = i * 16 + sR;
      const int l = (sP - (R >> 2)) & 3;
      gll16(Ap + (size_t)(m0 + R) * K + k0 + l * 8, As + i * 512);
      gll16(Bp + (size_t)(n0 + R) * K + k0 + l * 8, Bs + i * 512);
    }
    __syncthreads();
    short8_t a[4], b[4];
    #pragma unroll
    for (int ti = 0; ti < 4; ti++)
      a[ti] = *(const short8_t*)(As + (wm + ti * 16) * 32 + fbase);
    #pragma unroll
    for (int tj = 0; tj < 4; tj++)
      b[tj] = *(const short8_t*)(Bs + (wn + tj * 16) * 32 + fbase);
    #pragma unroll
    for (int ti = 0; ti < 4; ti++)
      #pragma unroll
      for (int tj = 0; tj < 4; tj++)
        acc[ti][tj] = __builtin_amdgcn_mfma_f32_16x16x32_bf16(
            a[ti], b[tj], acc[ti][tj], 0, 0, 0);
  }

  #pragma unroll
  for (int ti = 0; ti < 4; ti++) {
    const int mb = m0 + wm + ti * 16 + (lg << 2);     // 0..511, wave-uniform split
    const size_t obase = (mb >= 256 ? (size_t)NTOT : 0) + (size_t)bz * CPb;
    const int mc = mb & 255;
    #pragma unroll
    for (int tj = 0; tj < 4; tj++) {
      const int n = n0 + wn + tj * 16 + lm;
      uint2 o;
      o.x = pack2(acc[ti][tj][0] + bias[mb],     acc[ti][tj][1] + bias[mb + 1]);
      o.y = pack2(acc[ti][tj][2] + bias[mb + 2], acc[ti][tj][3] + bias[mb + 3]);
      *(uint2*)(Oq + obase + (size_t)n * 256 + mc) = o;
    }
  }
}

// ---------------------------------------------------------------------------
// PV GEMM: tile 128(M=chan) x 64(N=pixel), 4 waves 2x2 (each 64x32, acc 4x2).
// Round-12 proven config (BK=32, 12 KB LDS). XCD-swizzled block order: the
// x-pair sharing an St panel co-locates on one XCD's L2 (cuts HBM re-fetch).
// Epilogue: out = delta*acc + x (bf16 from xt, coalesced) -> attn_p [pos][256].
// ---------------------------------------------------------------------------
__global__ __launch_bounds__(256) void gemm_pv64(
    const unsigned short* __restrict__ A, long Ab,   // vbuf [c][i]
    const unsigned short* __restrict__ B, long Bb,   // St weights [j][i]
    int K,
    unsigned short* __restrict__ O,                  // attn_p
    const unsigned short* __restrict__ X,            // xt [b][p][c] bf16
    const float* __restrict__ delta, int bstart)
{
  const int t = threadIdx.x;
  const int ln = t & 63;
  const int wid = t >> 6;
  const int wm = (wid & 1) * 64, wn = (wid >> 1) * 32;
  const int lm = ln & 15, lg = ln >> 4;

  const int lin = swz_lin();
  const int lx = lin % (int)gridDim.x;
  const int rest = lin / (int)gridDim.x;
  const int ly = rest % (int)gridDim.y;
  const int lz = rest / (int)gridDim.y;

  const int m0 = lx * 128, n0 = ly * 64;
  const long bz = lz;
  const int b = bstart + (int)bz;
  const unsigned short* Ap = A + bz * Ab;
  const unsigned short* Bp = B + bz * Bb;

  __shared__ __align__(16) unsigned short As[128 * 32];
  __shared__ __align__(16) unsigned short Bs[64 * 32];

  const int sR = ln >> 2, sP = ln & 3;
  const int fbase = lm * 32 + (((lg + (lm >> 2)) & 3) * 8);

  f4_t acc[4][2];
  #pragma unroll
  for (int i = 0; i < 4; i++)
    #pragma unroll
    for (int j = 0; j < 2; j++) acc[i][j] = (f4_t){0.f, 0.f, 0.f, 0.f};

  for (int k0 = 0; k0 < K; k0 += 32) {
    __syncthreads();
    #pragma unroll
    for (int i = wid; i < 8; i += 4) {
      const int R = i * 16 + sR;
      const int l = (sP - (R >> 2)) & 3;
      gll16(Ap + (size_t)(m0 + R) * K + k0 + l * 8, As + i * 512);
    }
    {
      const int R = wid * 16 + sR;                    // 4 chunks, 1 per wave
      const int l = (sP - (R >> 2)) & 3;
      gll16(Bp + (size_t)(n0 + R) * K + k0 + l * 8, Bs + wid * 512);
    }
    __syncthreads();
    short8_t a[4], b8[2];
    #pragma unroll
    for (int ti = 0; ti < 4; ti++)
      a[ti] = *(const short8_t*)(As + (wm + ti * 16) * 32 + fbase);
    #pragma unroll
    for (int tj = 0; tj < 2; tj++)
      b8[tj] = *(const short8_t*)(Bs + (wn + tj * 16) * 32 + fbase);
    #pragma unroll
    for (int ti = 0; ti < 4; ti++)
      #pragma unroll
      for (int tj = 0; tj < 2; tj++)
        acc[ti][tj] = __builtin_amdgcn_mfma_f32_16x16x32_bf16(
            a[ti], b8[tj], acc[ti][tj], 0, 0, 0);
  }

  const float d0 = delta[0];
  #pragma unroll
  for (int ti = 0; ti < 4; ti++) {
    const int mb = m0 + wm + ti * 16 + (lg << 2);     // channel c
    #pragma unroll
    for (int tj = 0; tj < 2; tj++) {
      const int n = n0 + wn + tj * 16 + lm;            // pixel j
      const int y = n / 48, x = n - (n / 48) * 48;
      const size_t pp = (size_t)(y + 1) * 50 + (x + 1);
      const uint2 xv = *(const uint2*)(X + ((size_t)b * PPX + n) * 256 + mb);
      float fr[4];
      fr[0] = bf2f((unsigned short)(xv.x & 0xffffu));
      fr[1] = bf2f((unsigned short)(xv.x >> 16));
      fr[2] = bf2f((unsigned short)(xv.y & 0xffffu));
      fr[3] = bf2f((unsigned short)(xv.y >> 16));
      float vr[4];
      #pragma unroll
      for (int r = 0; r < 4; r++)
        vr[r] = d0 * acc[ti][tj][r] + fr[r];
      uint2 o;
      o.x = pack2(vr[0], vr[1]);
      o.y = pack2(vr[2], vr[3]);
      *(uint2*)(O + ((size_t)b * PADIMG + pp) * 256 + mb) = o;
    }
  }
}

// ---------------------------------------------------------------------------
// Row softmax of St IN PLACE: row j: W[i] = exp(s-mx)/sum  (bf16 out)
// ---------------------------------------------------------------------------
__global__ __launch_bounds__(256) void rowstats(
    unsigned short* __restrict__ St, long sstride)
{
  const int j = blockIdx.x, bb = blockIdx.y;
  unsigned short* row = St + (long)bb * sstride + (size_t)j * PPX;
  const int t = threadIdx.x;

  float v[16];
  int nv = 0;
  float m = -1e30f;
  for (int ch = t; ch < 288; ch += 256) {
    const uint4 d = *(const uint4*)(row + ch * 8);
    const unsigned int* dp = (const unsigned int*)&d;
    #pragma unroll
    for (int q = 0; q < 4; q++) {
      v[nv]     = bf2f((unsigned short)(dp[q] & 0xffffu));
      v[nv + 1] = bf2f((unsigned short)(dp[q] >> 16));
      m = fmaxf(m, fmaxf(v[nv], v[nv + 1]));
      nv += 2;
    }
  }
  #pragma unroll
  for (int off = 32; off > 0; off >>= 1)
    m = fmaxf(m, __shfl_xor(m, off));
  __shared__ float red[8];
  if ((t & 63) == 0) red[t >> 6] = m;
  __syncthreads();
  m = fmaxf(fmaxf(red[0], red[1]), fmaxf(red[2], red[3]));

  float sum = 0.f;
  for (int u = 0; u < nv; u++) { v[u] = __expf(v[u] - m); sum += v[u]; }
  #pragma unroll
  for (int off = 32; off > 0; off >>= 1)
    sum += __shfl_xor(sum, off);
  if ((t & 63) == 0) red[4 + (t >> 6)] = sum;
  __syncthreads();
  const float inv = 1.f / (red[4] + red[5] + red[6] + red[7]);

  int u = 0;
  for (int ch = t; ch < 288; ch += 256) {
    unsigned int res[4];
    #pragma unroll
    for (int q = 0; q < 4; q++) {
      res[q] = pack2(v[u] * inv, v[u + 1] * inv);
      u += 2;
    }
    *(uint4*)(row + ch * 8) = *(const uint4*)res;
  }
}

// ---------------------------------------------------------------------------
// Conv3x3 + BN + ReLU, MFMA bf16, [pos][chan] activations, async LDS staging.
// 256 thr (4 waves), tile 32 Cout x 192 px. Grid = 768 blocks = 3/CU.
// ---------------------------------------------------------------------------
template<bool OUT_BF16>
__global__ __launch_bounds__(256) void conv_mfma(
    const unsigned short* __restrict__ act_p, int Cin,
    const unsigned short* __restrict__ wr,
    const float* __restrict__ gamma, const float* __restrict__ beta,
    const float* __restrict__ mean,  const float* __restrict__ var,
    void* __restrict__ outv)
{
  const int t  = threadIdx.x;
  const int wv = t >> 6;          // wave 0..3 -> 48-px chunk
  const int ln = t & 63;
  const int lm = ln & 15;
  const int lg = ln >> 4;

  const int bx = blockIdx.x;      // 96 = 8 images * 12 pixel-tiles (192 px)
  const int bb = bx / 12;
  const int p0 = (bx % 12) * 192;
  const int m0 = blockIdx.y * 32; // 8 m-tiles of 32 Cout

  __shared__ __align__(16) unsigned short As[9 * 32 * 32]; // [tap][m][c] 18.4 KB
  __shared__ __align__(16) unsigned short Bs[304 * 32];    // [pos][c]    19.5 KB

  const int qbase = p0 + 2 * (p0 / 48);    // q(p0) - 51
  int qoff[3];
  #pragma unroll
  for (int tj = 0; tj < 3; tj++) {
    const int p = p0 + wv * 48 + tj * 16 + lm;
    qoff[tj] = (p - p0) + 2 * (p / 48 - p0 / 48) + 51;
  }

  const int sR = ln >> 2, sP = ln & 3;
  const int sl = (sP - (sR >> 2)) & 3;
  const int abase = lm * 32 + (((lg + (lm >> 2)) & 3) * 8);

  const unsigned short* gb = act_p + (size_t)bb * PADIMG * Cin + sl * 8;

  f4_t acc[2][3];
  #pragma unroll
  for (int i = 0; i < 2; i++)
    #pragma unroll
    for (int j = 0; j < 3; j++) acc[i][j] = (f4_t){0.f, 0.f, 0.f, 0.f};

  for (int c0 = 0; c0 < Cin; c0 += 32) {
    __syncthreads();
    for (int i = wv; i < 18; i += 4) {
      const int R = i * 16 + sR;                          // 0..287
      const int tap = R >> 5, mr = R & 31;
      const int l = (sP - (R >> 2)) & 3;
      gll16(wr + ((size_t)(tap * 256 + m0 + mr)) * Cin + c0 + l * 8, As + i * 512);
    }
    for (int i = wv; i < 19; i += 4) {
      const int R = i * 16 + sR;                          // 0..303
      int Rg = qbase + R;
      if (Rg > PADIMG - 1) Rg = PADIMG - 1;
      gll16(gb + (size_t)Rg * Cin + c0, Bs + i * 512);
    }
    __syncthreads();
    #pragma unroll
    for (int ky = 0; ky < 3; ky++) {
      #pragma unroll
      for (int kx = 0; kx < 3; kx++) {
        const int off = (ky - 1) * 50 + (kx - 1);
        const int tap = ky * 3 + kx;
        short8_t a[2], b[3];
        #pragma unroll
        for (int ti = 0; ti < 2; ti++)
          a[ti] = *(const short8_t*)(As + tap * 1024 + ti * 512 + abase);
        #pragma unroll
        for (int tj = 0; tj < 3; tj++) {
          const int R = qoff[tj] + off;
          const int slot = (lg + (R >> 2)) & 3;
          b[tj] = *(const short8_t*)(Bs + R * 32 + slot * 8);
        }
        #pragma unroll
        for (int ti = 0; ti < 2; ti++)
          #pragma unroll
          for (int tj = 0; tj < 3; tj++)
            acc[ti][tj] = __builtin_amdgcn_mfma_f32_16x16x32_bf16(
                a[ti], b[tj], acc[ti][tj], 0, 0, 0);
      }
    }
  }

  // ---- epilogue: BN + ReLU ----
  #pragma unroll
  for (int ti = 0; ti < 2; ti++) {
    const int m = m0 + ti * 16 + (lg << 2);
    float inv[4], add[4];
    #pragma unroll
    for (int r = 0; r < 4; r++) {
      inv[r] = gamma[m + r] * rsqrtf(var[m + r] + 1e-5f);
      add[r] = beta[m + r] - mean[m + r] * inv[r];
    }
    #pragma unroll
    for (int tj = 0; tj < 3; tj++) {
      const int p = p0 + wv * 48 + tj * 16 + lm;
      float vr[4];
      #pragma unroll
      for (int r = 0; r < 4; r++)
        vr[r] = relu_(acc[ti][tj][r] * inv[r] + add[r]);
      if (OUT_BF16) {
        uint2 o;
        o.x = pack2(vr[0], vr[1]);
        o.y = pack2(vr[2], vr[3]);
        *(uint2*)((unsigned short*)outv + ((size_t)(bb * PPX + p)) * 256 + m) = o;
      } else {
        #pragma unroll
        for (int r = 0; r < 4; r++)
          ((float*)outv)[((size_t)(bb * 256 + m + r)) * PPX + p] = vr[r];
      }
    }
  }
}

// ---------------------------------------------------------------------------
// pool3(avg/max of xt bf16) * sigmoid(act1) -> padded bf16 cat [pos][512]
// Vectorized: 8 channels per thread (uint4 loads/stores).
// ---------------------------------------------------------------------------
__global__ __launch_bounds__(256) void pool_gate_cat(
    const unsigned short* __restrict__ xt, const unsigned short* __restrict__ act1b,
    unsigned short* __restrict__ cat_p)
{
  const int idx = blockIdx.x * 256 + threadIdx.x;   // < NTOT/8
  const int cg = (idx & 31) * 8;
  const int rest = idx >> 5;
  const int p = rest % PPX;
  const int b = rest / PPX;
  const int y = p / 48, x = p - y * 48;
  const unsigned short* base = xt + ((size_t)b * PPX) * 256 + cg;
  float s[8], mx[8];
  #pragma unroll
  for (int e = 0; e < 8; e++) { s[e] = 0.f; mx[e] = -1e30f; }
  #pragma unroll
  for (int dy = -1; dy <= 1; dy++) {
    const int yy = y + dy;
    if (yy < 0 || yy >= 48) continue;
    #pragma unroll
    for (int dx = -1; dx <= 1; dx++) {
      const int xx = x + dx;
      if (xx < 0 || xx >= 48) continue;
      const uint4 d = *(const uint4*)&base[(size_t)(yy * 48 + xx) * 256];
      const unsigned int* dp = (const unsigned int*)&d;
      #pragma unroll
      for (int q = 0; q < 4; q++) {
        const float f0 = bf2f((unsigned short)(dp[q] & 0xffffu));
        const float f1 = bf2f((unsigned short)(dp[q] >> 16));
        s[2 * q] += f0; s[2 * q + 1] += f1;
        mx[2 * q] = fmaxf(mx[2 * q], f0);
        mx[2 * q + 1] = fmaxf(mx[2 * q + 1], f1);
      }
    }
  }
  const uint4 g4 = *(const uint4*)&act1b[((size_t)b * PPX + p) * 256 + cg];
  const unsigned int* gp = (const unsigned int*)&g4;
  unsigned int om[4], oa[4];
  #pragma unroll
  for (int q = 0; q < 4; q++) {
    const float g0 = bf2f((unsigned short)(gp[q] & 0xffffu));
    const float g1 = bf2f((unsigned short)(gp[q] >> 16));
    const float gt0 = 1.f / (1.f + __expf(-g0));
    const float gt1 = 1.f / (1.f + __expf(-g1));
    om[q] = pack2(mx[2 * q] * gt0, mx[2 * q + 1] * gt1);
    oa[q] = pack2(s[2 * q] * (1.f / 9.f) * gt0, s[2 * q + 1] * (1.f / 9.f) * gt1);
  }
  const size_t pp = (size_t)(y + 1) * 50 + (x + 1);
  unsigned short* crow = cat_p + ((size_t)b * PADIMG + pp) * 512 + cg;
  *(uint4*)crow = *(const uint4*)om;
  *(uint4*)(crow + 256) = *(const uint4*)oa;
}

// ---------------------------------------------------------------------------
extern "C" void kernel_launch(void* const* d_in, const int* in_sizes, int n_in,
                              void* d_out, int out_size, void* d_ws, size_t ws_size,
                              hipStream_t stream)
{
  const float* ftr  = (const float*)d_in[0];
  const float* wq   = (const float*)d_in[1];
  const float* bq   = (const float*)d_in[2];
  const float* wk   = (const float*)d_in[3];
  const float* bk   = (const float*)d_in[4];
  const float* wv   = (const float*)d_in[5];
  const float* bv   = (const float*)d_in[6];
  const float* delta= (const float*)d_in[7];
  const float* w1   = (const float*)d_in[8];
  const float* g1   = (const float*)d_in[9];
  const float* b1   = (const float*)d_in[10];
  const float* m1   = (const float*)d_in[11];
  const float* v1   = (const float*)d_in[12];
  const float* w2   = (const float*)d_in[13];
  const float* g2   = (const float*)d_in[14];
  const float* b2   = (const float*)d_in[15];
  const float* m2   = (const float*)d_in[16];
  const float* v2   = (const float*)d_in[17];
  float* out = (float*)d_out;

  // ---- workspace layout (shorts) ----
  const size_t XT = (size_t)NTOT;
  unsigned short* base = (unsigned short*)d_ws;
  unsigned short* xt   = base;
  unsigned short* qt   = xt  + XT;
  unsigned short* kt   = qt  + XT;        // MUST stay qt + NTOT (gemm_qk2 relies on it)
  unsigned short* vbuf = kt  + XT;
  unsigned short* wqb  = vbuf + XT;
  unsigned short* wkb  = wqb + 65536;     // MUST stay wqb + 65536 (contiguous A)
  unsigned short* wvb  = wkb + 65536;
  unsigned short* wr1  = wvb + 65536;
  unsigned short* wr2  = wr1 + (size_t)9 * 256 * 256;
  unsigned short* attn_p = wr2 + (size_t)9 * 256 * 512;        // [b][2500][256]
  unsigned short* act1b  = attn_p + (size_t)NB * PADIMG * 256; // [b][2304][256]
  unsigned short* cat_p  = act1b + XT;                         // [b][2500][512]
  unsigned short* St     = cat_p + (size_t)NB * PADIMG * 512;

  // bqk (512 floats) overlays act1b (unused until conv1)
  float* bqk = (float*)act1b;

  const size_t head_bytes = (size_t)((char*)St - (char*)base);
  const bool modeA = ws_size >= head_bytes + (size_t)NB * PSQ * 2;

  // ---- weight preps ----
  castw<<<dim3(256), 256, 0, stream>>>(wq, wqb, 65536);
  castw<<<dim3(256), 256, 0, stream>>>(wk, wkb, 65536);
  castw<<<dim3(256), 256, 0, stream>>>(wv, wvb, 65536);
  biascat<<<dim3(2), 256, 0, stream>>>(bq, bk, bqk);
  repack_w<<<dim3((9 * 256 * 256 + 255) / 256), 256, 0, stream>>>(w1, wr1, 256);
  repack_w<<<dim3((9 * 256 * 512 + 255) / 256), 256, 0, stream>>>(w2, wr2, 512);

  // ---- x transpose ----
  transpose_cast<<<dim3(36, 4, 8), 256, 0, stream>>>(ftr, xt);

  // ---- QKV: merged Q+K (576 blocks), V separate ----
  gemm_qk2<<<dim3(4, 18, 8), 256, 0, stream>>>(wqb, xt, (long)CPb, qt, bqk);
  gemm_nt<2><<<dim3(18, 2, 8), 256, 0, stream>>>(
      xt, (long)CPb, wvb, 0L, 256, vbuf, (long)CPb, PPX, bv);

  // ---- clear ONLY attn_p borders (interior fully overwritten by PV) ----
  border_clear<<<dim3(196), 256, 0, stream>>>(attn_p, 256);

  if (modeA) {
    gemm_s<<<dim3(18, 18, 8), 256, 0, stream>>>(
        qt, (long)CPb, kt, (long)CPb, St, (long)PSQ, PPX);
    rowstats<<<dim3(PPX, 8), 256, 0, stream>>>(St, (long)PSQ);
    gemm_pv64<<<dim3(2, 36, 8), 256, 0, stream>>>(
        vbuf, (long)CPb, St, (long)PSQ, PPX, attn_p, xt, delta, 0);
  } else {
    for (int b = 0; b < NB; b++) {
      gemm_s<<<dim3(18, 18, 1), 256, 0, stream>>>(
          qt + (size_t)b * CPb, 0L, kt + (size_t)b * CPb, 0L, St, 0L, PPX);
      rowstats<<<dim3(PPX, 1), 256, 0, stream>>>(St, 0L);
      gemm_pv64<<<dim3(2, 36, 1), 256, 0, stream>>>(
          vbuf + (size_t)b * CPb, 0L, St, 0L, PPX, attn_p, xt, delta, b);
    }
  }

  // ---- conv1 + BN + ReLU -> bf16 act1b [p][c] ----
  conv_mfma<true><<<dim3(96, 8), 256, 0, stream>>>(
      attn_p, 256, wr1, g1, b1, m1, v1, (void*)act1b);

  // ---- clear ONLY cat_p borders, then pool + gate + concat ----
  border_clear<<<dim3(392), 256, 0, stream>>>(cat_p, 512);
  pool_gate_cat<<<dim3(NTOT / 8 / 256), 256, 0, stream>>>(xt, act1b, cat_p);

  // ---- conv2 + BN + ReLU -> fp32 out ----
  conv_mfma<false><<<dim3(96, 8), 256, 0, stream>>>(
      cat_p, 512, wr2, g2, b2, m2, v2, (void*)out);
}

// Round 16
// 370.316 us; speedup vs baseline: 1.0734x; 1.0263x over previous
//
#include <hip/hip_runtime.h>
#include <math.h>

// Problem constants
#define NB   8
#define CCH  256
#define PPX  2304            // 48*48
#define CPb  (CCH*PPX)       // per-batch C*P = 589824
#define NTOT (NB*CPb)        // 4718592
#define PSQ  (PPX*PPX)       // 5308416
#define PADIMG 2500          // 50*50 padded image

typedef short short8_t __attribute__((ext_vector_type(8)));
typedef float f4_t __attribute__((ext_vector_type(4)));

__device__ __forceinline__ float relu_(float x){ return x > 0.f ? x : 0.f; }

__device__ __forceinline__ unsigned short f2bf(float f) {
  unsigned int u = __builtin_bit_cast(unsigned int, f);
  u += 0x7fffu + ((u >> 16) & 1u);
  return (unsigned short)(u >> 16);
}
__device__ __forceinline__ float bf2f(unsigned short h) {
  unsigned int u = ((unsigned int)h) << 16;
  return __builtin_bit_cast(float, u);
}
__device__ __forceinline__ unsigned int pack2(float a, float b) {
  return (unsigned int)f2bf(a) | ((unsigned int)f2bf(b) << 16);
}

// async global -> LDS, 16B per lane, wave-uniform LDS base (lane spreads x16B)
__device__ __forceinline__ void gll16(const void* g, void* l) {
  __builtin_amdgcn_global_load_lds(
      (const __attribute__((address_space(1))) unsigned int*)g,
      (__attribute__((address_space(3))) unsigned int*)l, 16, 0, 0);
}

// XCD-aware chunked block swizzle (T1): consecutive LOGICAL blocks land on
// the same XCD's L2. Bijective when total%8==0, else identity (ERRATA #11).
__device__ __forceinline__ int swz_lin() {
  const int L = (int)(blockIdx.x + gridDim.x * (blockIdx.y + gridDim.y * blockIdx.z));
  const int total = (int)(gridDim.x * gridDim.y * gridDim.z);
  if ((total & 7) == 0) {
    const int q = total >> 3;
    return (L & 7) * q + (L >> 3);
  }
  return L;
}

// ---------------------------------------------------------------------------
// ONE merged prep kernel: casts, bias concat, weight repacks, border clears.
// Segment arithmetic byte-identical to the kernels it replaces.
//   seg0..2: castw wq/wk/wv (65536 each)
//   seg3:    biascat (512)
//   seg4:    repack w1 (Cin=256, 589824)
//   seg5:    repack w2 (Cin=512, 1179648)
//   seg6:    border attn_p (C=256, NB*196*32 uint4)
//   seg7:    border cat_p  (C=512, NB*196*64 uint4)
// ---------------------------------------------------------------------------
#define PN0 65536
#define PN3 512
#define PN4 (9*256*256)
#define PN5 (9*256*512)
#define PN6 (NB*196*32)
#define PN7 (NB*196*64)
#define POFF1 (PN0)
#define POFF2 (2*PN0)
#define POFF3 (3*PN0)
#define POFF4 (3*PN0 + PN3)
#define POFF5 (POFF4 + PN4)
#define POFF6 (POFF5 + PN5)
#define POFF7 (POFF6 + PN6)
#define PTOT  (POFF7 + PN7)

__global__ __launch_bounds__(256) void prep(
    const float* __restrict__ wq, const float* __restrict__ wk,
    const float* __restrict__ wv,
    const float* __restrict__ bq, const float* __restrict__ bk,
    const float* __restrict__ w1, const float* __restrict__ w2,
    unsigned short* __restrict__ wqb, unsigned short* __restrict__ wkb,
    unsigned short* __restrict__ wvb, float* __restrict__ bqk,
    unsigned short* __restrict__ wr1, unsigned short* __restrict__ wr2,
    unsigned short* __restrict__ attn_p, unsigned short* __restrict__ cat_p)
{
  int idx = blockIdx.x * 256 + threadIdx.x;
  if (idx >= PTOT) return;
  if (idx < POFF1) { wqb[idx] = f2bf(wq[idx]); return; }
  if (idx < POFF2) { const int i = idx - POFF1; wkb[i] = f2bf(wk[i]); return; }
  if (idx < POFF3) { const int i = idx - POFF2; wvb[i] = f2bf(wv[i]); return; }
  if (idx < POFF4) {
    const int i = idx - POFF3;
    bqk[i] = (i < 256) ? bq[i] : bk[i - 256];
    return;
  }
  if (idx < POFF5) {
    const int i = idx - POFF4;               // repack w1, Cin=256
    const int c = i % 256;
    const int rest = i / 256;
    const int o = rest % 256;
    const int tap = rest / 256;
    wr1[i] = f2bf(w1[((size_t)o * 256 + c) * 9 + tap]);
    return;
  }
  if (idx < POFF6) {
    const int i = idx - POFF5;               // repack w2, Cin=512
    const int c = i % 512;
    const int rest = i / 512;
    const int o = rest % 256;
    const int tap = rest / 256;
    wr2[i] = f2bf(w2[((size_t)o * 512 + c) * 9 + tap]);
    return;
  }
  // border clears (uint4 granularity)
  unsigned short* p;
  int C, r;
  if (idx < POFF7) { p = attn_p; C = 256; r = idx - POFF6; }
  else             { p = cat_p;  C = 512; r = idx - POFF7; }
  const int v4 = C >> 3;
  const int perB = 196 * v4;
  const int b = r / perB;
  const int rr = r - b * perB;
  const int pos = rr / v4;
  const int co = (rr - pos * v4) * 8;
  int pp;
  if (pos < 50)        pp = pos;                                   // row 0
  else if (pos < 100)  pp = 2450 + (pos - 50);                     // row 49
  else { const int j = pos - 100; pp = (1 + (j >> 1)) * 50 + (j & 1) * 49; }
  uint4 z; z.x = 0; z.y = 0; z.z = 0; z.w = 0;
  *(uint4*)(p + ((size_t)b * PADIMG + pp) * C + co) = z;
}

// ftr [b][c][p] fp32 -> x_t [b][p][c] bf16
__global__ __launch_bounds__(256) void transpose_cast(
    const float* __restrict__ ftr, unsigned short* __restrict__ xt)
{
  const int p0 = blockIdx.x * 64, c0 = blockIdx.y * 64, b = blockIdx.z;
  const int t = threadIdx.x;
  __shared__ unsigned short T[64][72];
  #pragma unroll
  for (int pass = 0; pass < 4; pass++) {
    const int cr = pass * 16 + (t >> 4);
    const int pc = (t & 15) * 4;
    float4 v = *(const float4*)&ftr[((size_t)(b * 256 + c0 + cr)) * PPX + p0 + pc];
    T[pc + 0][cr] = f2bf(v.x); T[pc + 1][cr] = f2bf(v.y);
    T[pc + 2][cr] = f2bf(v.z); T[pc + 3][cr] = f2bf(v.w);
  }
  __syncthreads();
  #pragma unroll
  for (int pass = 0; pass < 2; pass++) {
    const int pr = pass * 32 + (t >> 3);
    const int cc = (t & 7) * 8;
    *(uint4*)&xt[((size_t)(b * PPX + p0 + pr)) * 256 + c0 + cc] = *(const uint4*)&T[pr][cc];
  }
}

// ---------------------------------------------------------------------------
// Generic bf16 MFMA GEMM: O[n][m] = sum_k A[m][k]*B[n][k]
// Tile 128x128, 4 waves (2x2 of 64x64). Round-3 proven schedule.
// EPI: 2 bias on n (V gemm only)
// ---------------------------------------------------------------------------
template<int EPI>
__global__ __launch_bounds__(256) void gemm_nt(
    const unsigned short* __restrict__ A, long Ab,
    const unsigned short* __restrict__ B, long Bb, int K,
    unsigned short* __restrict__ O, long Ob, int ldo,
    const float* __restrict__ bias)
{
  const int t = threadIdx.x;
  const int ln = t & 63;
  const int wid = t >> 6;
  const int wm = (wid & 1) * 64, wn = (wid >> 1) * 64;
  const int lm = ln & 15, lg = ln >> 4;
  const int m0 = blockIdx.x * 128, n0 = blockIdx.y * 128;
  const long bz = blockIdx.z;
  const unsigned short* Ap = A + bz * Ab;
  const unsigned short* Bp = B + bz * Bb;

  __shared__ __align__(16) unsigned short As[128 * 32];
  __shared__ __align__(16) unsigned short Bs[128 * 32];

  const int sR = ln >> 2, sP = ln & 3;
  const int fbase = lm * 32 + (((lg + (lm >> 2)) & 3) * 8);

  f4_t acc[4][4];
  #pragma unroll
  for (int i = 0; i < 4; i++)
    #pragma unroll
    for (int j = 0; j < 4; j++) acc[i][j] = (f4_t){0.f, 0.f, 0.f, 0.f};

  for (int k0 = 0; k0 < K; k0 += 32) {
    __syncthreads();
    #pragma unroll
    for (int i = wid; i < 8; i += 4) {
      const int R = i * 16 + sR;
      const int l = (sP - (R >> 2)) & 3;              // logical chan-group
      gll16(Ap + (size_t)(m0 + R) * K + k0 + l * 8, As + i * 512);
      gll16(Bp + (size_t)(n0 + R) * K + k0 + l * 8, Bs + i * 512);
    }
    __syncthreads();
    short8_t a[4], b[4];
    #pragma unroll
    for (int ti = 0; ti < 4; ti++)
      a[ti] = *(const short8_t*)(As + (wm + ti * 16) * 32 + fbase);
    #pragma unroll
    for (int tj = 0; tj < 4; tj++)
      b[tj] = *(const short8_t*)(Bs + (wn + tj * 16) * 32 + fbase);
    #pragma unroll
    for (int ti = 0; ti < 4; ti++)
      #pragma unroll
      for (int tj = 0; tj < 4; tj++)
        acc[ti][tj] = __builtin_amdgcn_mfma_f32_16x16x32_bf16(
            a[ti], b[tj], acc[ti][tj], 0, 0, 0);
  }

  #pragma unroll
  for (int ti = 0; ti < 4; ti++) {
    const int mb = m0 + wm + ti * 16 + (lg << 2);
    #pragma unroll
    for (int tj = 0; tj < 4; tj++) {
      const int n = n0 + wn + tj * 16 + lm;
      float add0 = 0.f, add1 = 0.f, add2 = 0.f, add3 = 0.f;
      if (EPI == 2) { add0 = add1 = add2 = add3 = bias[n]; }
      uint2 o;
      o.x = pack2(acc[ti][tj][0] + add0, acc[ti][tj][1] + add1);
      o.y = pack2(acc[ti][tj][2] + add2, acc[ti][tj][3] + add3);
      *(uint2*)(O + bz * Ob + (size_t)n * ldo + mb) = o;
    }
  }
}

// ---------------------------------------------------------------------------
// QK^T GEMM, tile 128x128, BK=64: two 32-chan sub-slices staged per barrier,
// 32 MFMA per wave per iteration, 36 barriers. 32 KB LDS, acc 4x4.
// XCD-swizzled block order.
// ---------------------------------------------------------------------------
__global__ __launch_bounds__(256) void gemm_s(
    const unsigned short* __restrict__ A, long Ab,
    const unsigned short* __restrict__ B, long Bb,
    unsigned short* __restrict__ O, long Ob, int ldo)
{
  const int K = 256;
  const int t = threadIdx.x;
  const int ln = t & 63;
  const int wid = t >> 6;
  const int wm = (wid & 1) * 64, wn = (wid >> 1) * 64;
  const int lm = ln & 15, lg = ln >> 4;

  const int lin = swz_lin();
  const int lx = lin % (int)gridDim.x;
  const int rest = lin / (int)gridDim.x;
  const int ly = rest % (int)gridDim.y;
  const int lz = rest / (int)gridDim.y;

  const int m0 = lx * 128, n0 = ly * 128;
  const long bz = lz;
  const unsigned short* Ap = A + bz * Ab;
  const unsigned short* Bp = B + bz * Bb;

  __shared__ __align__(16) unsigned short As[2][128 * 32];
  __shared__ __align__(16) unsigned short Bs[2][128 * 32];

  const int sR = ln >> 2, sP = ln & 3;
  const int fbase = lm * 32 + (((lg + (lm >> 2)) & 3) * 8);

  f4_t acc[4][4];
  #pragma unroll
  for (int i = 0; i < 4; i++)
    #pragma unroll
    for (int j = 0; j < 4; j++) acc[i][j] = (f4_t){0.f, 0.f, 0.f, 0.f};

  for (int k0 = 0; k0 < K; k0 += 64) {
    __syncthreads();
    #pragma unroll
    for (int s = 0; s < 2; s++) {
      #pragma unroll
      for (int i = wid; i < 8; i += 4) {
        const int R = i * 16 + sR;
        const int l = (sP - (R >> 2)) & 3;
        gll16(Ap + (size_t)(m0 + R) * K + k0 + s * 32 + l * 8, &As[s][i * 512]);
        gll16(Bp + (size_t)(n0 + R) * K + k0 + s * 32 + l * 8, &Bs[s][i * 512]);
      }
    }
    __syncthreads();
    #pragma unroll
    for (int s = 0; s < 2; s++) {
      short8_t a[4], b[4];
      #pragma unroll
      for (int ti = 0; ti < 4; ti++)
        a[ti] = *(const short8_t*)(&As[s][(wm + ti * 16) * 32 + fbase]);
      #pragma unroll
      for (int tj = 0; tj < 4; tj++)
        b[tj] = *(const short8_t*)(&Bs[s][(wn + tj * 16) * 32 + fbase]);
      #pragma unroll
      for (int ti = 0; ti < 4; ti++)
        #pragma unroll
        for (int tj = 0; tj < 4; tj++)
          acc[ti][tj] = __builtin_amdgcn_mfma_f32_16x16x32_bf16(
              a[ti], b[tj], acc[ti][tj], 0, 0, 0);
    }
  }

  #pragma unroll
  for (int ti = 0; ti < 4; ti++) {
    const int mb = m0 + wm + ti * 16 + (lg << 2);
    #pragma unroll
    for (int tj = 0; tj < 4; tj++) {
      const int n = n0 + wn + tj * 16 + lm;
      uint2 o;
      o.x = pack2(acc[ti][tj][0], acc[ti][tj][1]);
      o.y = pack2(acc[ti][tj][2], acc[ti][tj][3]);
      *(uint2*)(O + bz * Ob + (size_t)n * ldo + mb) = o;
    }
  }
}

// ---------------------------------------------------------------------------
// Merged Q+K GEMM (standalone clone of gemm_nt): A = wqb||wkb [512][256],
// B = xt. Rows 0..255 -> qt, 256..511 -> kt (= qt + NTOT).
// ---------------------------------------------------------------------------
__global__ __launch_bounds__(256) void gemm_qk2(
    const unsigned short* __restrict__ A,
    const unsigned short* __restrict__ B, long Bb,
    unsigned short* __restrict__ Oq,
    const float* __restrict__ bias)
{
  const int t = threadIdx.x;
  const int ln = t & 63;
  const int wid = t >> 6;
  const int wm = (wid & 1) * 64, wn = (wid >> 1) * 64;
  const int lm = ln & 15, lg = ln >> 4;
  const int m0 = blockIdx.x * 128, n0 = blockIdx.y * 128;
  const long bz = blockIdx.z;
  const int K = 256;
  const unsigned short* Ap = A;
  const unsigned short* Bp = B + bz * Bb;

  __shared__ __align__(16) unsigned short As[128 * 32];
  __shared__ __align__(16) unsigned short Bs[128 * 32];

  const int sR = ln >> 2, sP = ln & 3;
  const int fbase = lm * 32 + (((lg + (lm >> 2)) & 3) * 8);

  f4_t acc[4][4];
  #pragma unroll
  for (int i = 0; i < 4; i++)
    #pragma unroll
    for (int j = 0; j < 4; j++) acc[i][j] = (f4_t){0.f, 0.f, 0.f, 0.f};

  for (int k0 = 0; k0 < K; k0 += 32) {
    __syncthreads();
    #pragma unroll
    for (int i = wid; i < 8; i += 4) {
      const int R = i * 16 + sR;
      const int l = (sP - (R >> 2)) & 3;
      gll16(Ap + (size_t)(m0 + R) * K + k0 + l * 8, As + i * 512);
      gll16(Bp + (size_t)(n0 + R) * K + k0 + l * 8, Bs + i * 512);
    }
    __syncthreads();
    short8_t a[4], b[4];
    #pragma unroll
    for (int ti = 0; ti < 4; ti++)
      a[ti] = *(const short8_t*)(As + (wm + ti * 16) * 32 + fbase);
    #pragma unroll
    for (int tj = 0; tj < 4; tj++)
      b[tj] = *(const short8_t*)(Bs + (wn + tj * 16) * 32 + fbase);
    #pragma unroll
    for (int ti = 0; ti < 4; ti++)
      #pragma unroll
      for (int tj = 0; tj < 4; tj++)
        acc[ti][tj] = __builtin_amdgcn_mfma_f32_16x16x32_bf16(
            a[ti], b[tj], acc[ti][tj], 0, 0, 0);
  }

  #pragma unroll
  for (int ti = 0; ti < 4; ti++) {
    const int mb = m0 + wm + ti * 16 + (lg << 2);     // 0..511, wave-uniform split
    const size_t obase = (mb >= 256 ? (size_t)NTOT : 0) + (size_t)bz * CPb;
    const int mc = mb & 255;
    #pragma unroll
    for (int tj = 0; tj < 4; tj++) {
      const int n = n0 + wn + tj * 16 + lm;
      uint2 o;
      o.x = pack2(acc[ti][tj][0] + bias[mb],     acc[ti][tj][1] + bias[mb + 1]);
      o.y = pack2(acc[ti][tj][2] + bias[mb + 2], acc[ti][tj][3] + bias[mb + 3]);
      *(uint2*)(Oq + obase + (size_t)n * 256 + mc) = o;
    }
  }
}

// ---------------------------------------------------------------------------
// PV GEMM: tile 128(M=chan) x 64(N=pixel), 4 waves 2x2 (each 64x32, acc 4x2).
// BK=32, 12 KB LDS, XCD-swizzled (St x-pair shares one XCD's L2).
// Epilogue: out = delta*acc + x (bf16 from xt, coalesced) -> attn_p [pos][256].
// ---------------------------------------------------------------------------
__global__ __launch_bounds__(256) void gemm_pv64(
    const unsigned short* __restrict__ A, long Ab,   // vbuf [c][i]
    const unsigned short* __restrict__ B, long Bb,   // St weights [j][i]
    int K,
    unsigned short* __restrict__ O,                  // attn_p
    const unsigned short* __restrict__ X,            // xt [b][p][c] bf16
    const float* __restrict__ delta, int bstart)
{
  const int t = threadIdx.x;
  const int ln = t & 63;
  const int wid = t >> 6;
  const int wm = (wid & 1) * 64, wn = (wid >> 1) * 32;
  const int lm = ln & 15, lg = ln >> 4;

  const int lin = swz_lin();
  const int lx = lin % (int)gridDim.x;
  const int rest = lin / (int)gridDim.x;
  const int ly = rest % (int)gridDim.y;
  const int lz = rest / (int)gridDim.y;

  const int m0 = lx * 128, n0 = ly * 64;
  const long bz = lz;
  const int b = bstart + (int)bz;
  const unsigned short* Ap = A + bz * Ab;
  const unsigned short* Bp = B + bz * Bb;

  __shared__ __align__(16) unsigned short As[128 * 32];
  __shared__ __align__(16) unsigned short Bs[64 * 32];

  const int sR = ln >> 2, sP = ln & 3;
  const int fbase = lm * 32 + (((lg + (lm >> 2)) & 3) * 8);

  f4_t acc[4][2];
  #pragma unroll
  for (int i = 0; i < 4; i++)
    #pragma unroll
    for (int j = 0; j < 2; j++) acc[i][j] = (f4_t){0.f, 0.f, 0.f, 0.f};

  for (int k0 = 0; k0 < K; k0 += 32) {
    __syncthreads();
    #pragma unroll
    for (int i = wid; i < 8; i += 4) {
      const int R = i * 16 + sR;
      const int l = (sP - (R >> 2)) & 3;
      gll16(Ap + (size_t)(m0 + R) * K + k0 + l * 8, As + i * 512);
    }
    {
      const int R = wid * 16 + sR;                    // 4 chunks, 1 per wave
      const int l = (sP - (R >> 2)) & 3;
      gll16(Bp + (size_t)(n0 + R) * K + k0 + l * 8, Bs + wid * 512);
    }
    __syncthreads();
    short8_t a[4], b8[2];
    #pragma unroll
    for (int ti = 0; ti < 4; ti++)
      a[ti] = *(const short8_t*)(As + (wm + ti * 16) * 32 + fbase);
    #pragma unroll
    for (int tj = 0; tj < 2; tj++)
      b8[tj] = *(const short8_t*)(Bs + (wn + tj * 16) * 32 + fbase);
    #pragma unroll
    for (int ti = 0; ti < 4; ti++)
      #pragma unroll
      for (int tj = 0; tj < 2; tj++)
        acc[ti][tj] = __builtin_amdgcn_mfma_f32_16x16x32_bf16(
            a[ti], b8[tj], acc[ti][tj], 0, 0, 0);
  }

  const float d0 = delta[0];
  #pragma unroll
  for (int ti = 0; ti < 4; ti++) {
    const int mb = m0 + wm + ti * 16 + (lg << 2);     // channel c
    #pragma unroll
    for (int tj = 0; tj < 2; tj++) {
      const int n = n0 + wn + tj * 16 + lm;            // pixel j
      const int y = n / 48, x = n - (n / 48) * 48;
      const size_t pp = (size_t)(y + 1) * 50 + (x + 1);
      const uint2 xv = *(const uint2*)(X + ((size_t)b * PPX + n) * 256 + mb);
      float fr[4];
      fr[0] = bf2f((unsigned short)(xv.x & 0xffffu));
      fr[1] = bf2f((unsigned short)(xv.x >> 16));
      fr[2] = bf2f((unsigned short)(xv.y & 0xffffu));
      fr[3] = bf2f((unsigned short)(xv.y >> 16));
      float vr[4];
      #pragma unroll
      for (int r = 0; r < 4; r++)
        vr[r] = d0 * acc[ti][tj][r] + fr[r];
      uint2 o;
      o.x = pack2(vr[0], vr[1]);
      o.y = pack2(vr[2], vr[3]);
      *(uint2*)(O + ((size_t)b * PADIMG + pp) * 256 + mb) = o;
    }
  }
}

// ---------------------------------------------------------------------------
// Row softmax of St IN PLACE: row j: W[i] = exp(s-mx)/sum  (bf16 out)
// ---------------------------------------------------------------------------
__global__ __launch_bounds__(256) void rowstats(
    unsigned short* __restrict__ St, long sstride)
{
  const int j = blockIdx.x, bb = blockIdx.y;
  unsigned short* row = St + (long)bb * sstride + (size_t)j * PPX;
  const int t = threadIdx.x;

  float v[16];
  int nv = 0;
  float m = -1e30f;
  for (int ch = t; ch < 288; ch += 256) {
    const uint4 d = *(const uint4*)(row + ch * 8);
    const unsigned int* dp = (const unsigned int*)&d;
    #pragma unroll
    for (int q = 0; q < 4; q++) {
      v[nv]     = bf2f((unsigned short)(dp[q] & 0xffffu));
      v[nv + 1] = bf2f((unsigned short)(dp[q] >> 16));
      m = fmaxf(m, fmaxf(v[nv], v[nv + 1]));
      nv += 2;
    }
  }
  #pragma unroll
  for (int off = 32; off > 0; off >>= 1)
    m = fmaxf(m, __shfl_xor(m, off));
  __shared__ float red[8];
  if ((t & 63) == 0) red[t >> 6] = m;
  __syncthreads();
  m = fmaxf(fmaxf(red[0], red[1]), fmaxf(red[2], red[3]));

  float sum = 0.f;
  for (int u = 0; u < nv; u++) { v[u] = __expf(v[u] - m); sum += v[u]; }
  #pragma unroll
  for (int off = 32; off > 0; off >>= 1)
    sum += __shfl_xor(sum, off);
  if ((t & 63) == 0) red[4 + (t >> 6)] = sum;
  __syncthreads();
  const float inv = 1.f / (red[4] + red[5] + red[6] + red[7]);

  int u = 0;
  for (int ch = t; ch < 288; ch += 256) {
    unsigned int res[4];
    #pragma unroll
    for (int q = 0; q < 4; q++) {
      res[q] = pack2(v[u] * inv, v[u + 1] * inv);
      u += 2;
    }
    *(uint4*)(row + ch * 8) = *(const uint4*)res;
  }
}

// ---------------------------------------------------------------------------
// Conv3x3 + BN + ReLU, MFMA bf16, [pos][chan] activations, async LDS staging.
// 256 thr (4 waves), tile 32 Cout x 192 px. Grid = 768 blocks = 3/CU.
// ---------------------------------------------------------------------------
template<bool OUT_BF16>
__global__ __launch_bounds__(256) void conv_mfma(
    const unsigned short* __restrict__ act_p, int Cin,
    const unsigned short* __restrict__ wr,
    const float* __restrict__ gamma, const float* __restrict__ beta,
    const float* __restrict__ mean,  const float* __restrict__ var,
    void* __restrict__ outv)
{
  const int t  = threadIdx.x;
  const int wv = t >> 6;          // wave 0..3 -> 48-px chunk
  const int ln = t & 63;
  const int lm = ln & 15;
  const int lg = ln >> 4;

  const int bx = blockIdx.x;      // 96 = 8 images * 12 pixel-tiles (192 px)
  const int bb = bx / 12;
  const int p0 = (bx % 12) * 192;
  const int m0 = blockIdx.y * 32; // 8 m-tiles of 32 Cout

  __shared__ __align__(16) unsigned short As[9 * 32 * 32]; // [tap][m][c] 18.4 KB
  __shared__ __align__(16) unsigned short Bs[304 * 32];    // [pos][c]    19.5 KB

  const int qbase = p0 + 2 * (p0 / 48);    // q(p0) - 51
  int qoff[3];
  #pragma unroll
  for (int tj = 0; tj < 3; tj++) {
    const int p = p0 + wv * 48 + tj * 16 + lm;
    qoff[tj] = (p - p0) + 2 * (p / 48 - p0 / 48) + 51;
  }

  const int sR = ln >> 2, sP = ln & 3;
  const int sl = (sP - (sR >> 2)) & 3;
  const int abase = lm * 32 + (((lg + (lm >> 2)) & 3) * 8);

  const unsigned short* gb = act_p + (size_t)bb * PADIMG * Cin + sl * 8;

  f4_t acc[2][3];
  #pragma unroll
  for (int i = 0; i < 2; i++)
    #pragma unroll
    for (int j = 0; j < 3; j++) acc[i][j] = (f4_t){0.f, 0.f, 0.f, 0.f};

  for (int c0 = 0; c0 < Cin; c0 += 32) {
    __syncthreads();
    for (int i = wv; i < 18; i += 4) {
      const int R = i * 16 + sR;                          // 0..287
      const int tap = R >> 5, mr = R & 31;
      const int l = (sP - (R >> 2)) & 3;
      gll16(wr + ((size_t)(tap * 256 + m0 + mr)) * Cin + c0 + l * 8, As + i * 512);
    }
    for (int i = wv; i < 19; i += 4) {
      const int R = i * 16 + sR;                          // 0..303
      int Rg = qbase + R;
      if (Rg > PADIMG - 1) Rg = PADIMG - 1;
      gll16(gb + (size_t)Rg * Cin + c0, Bs + i * 512);
    }
    __syncthreads();
    #pragma unroll
    for (int ky = 0; ky < 3; ky++) {
      #pragma unroll
      for (int kx = 0; kx < 3; kx++) {
        const int off = (ky - 1) * 50 + (kx - 1);
        const int tap = ky * 3 + kx;
        short8_t a[2], b[3];
        #pragma unroll
        for (int ti = 0; ti < 2; ti++)
          a[ti] = *(const short8_t*)(As + tap * 1024 + ti * 512 + abase);
        #pragma unroll
        for (int tj = 0; tj < 3; tj++) {
          const int R = qoff[tj] + off;
          const int slot = (lg + (R >> 2)) & 3;
          b[tj] = *(const short8_t*)(Bs + R * 32 + slot * 8);
        }
        #pragma unroll
        for (int ti = 0; ti < 2; ti++)
          #pragma unroll
          for (int tj = 0; tj < 3; tj++)
            acc[ti][tj] = __builtin_amdgcn_mfma_f32_16x16x32_bf16(
                a[ti], b[tj], acc[ti][tj], 0, 0, 0);
      }
    }
  }

  // ---- epilogue: BN + ReLU ----
  #pragma unroll
  for (int ti = 0; ti < 2; ti++) {
    const int m = m0 + ti * 16 + (lg << 2);
    float inv[4], add[4];
    #pragma unroll
    for (int r = 0; r < 4; r++) {
      inv[r] = gamma[m + r] * rsqrtf(var[m + r] + 1e-5f);
      add[r] = beta[m + r] - mean[m + r] * inv[r];
    }
    #pragma unroll
    for (int tj = 0; tj < 3; tj++) {
      const int p = p0 + wv * 48 + tj * 16 + lm;
      float vr[4];
      #pragma unroll
      for (int r = 0; r < 4; r++)
        vr[r] = relu_(acc[ti][tj][r] * inv[r] + add[r]);
      if (OUT_BF16) {
        uint2 o;
        o.x = pack2(vr[0], vr[1]);
        o.y = pack2(vr[2], vr[3]);
        *(uint2*)((unsigned short*)outv + ((size_t)(bb * PPX + p)) * 256 + m) = o;
      } else {
        #pragma unroll
        for (int r = 0; r < 4; r++)
          ((float*)outv)[((size_t)(bb * 256 + m + r)) * PPX + p] = vr[r];
      }
    }
  }
}

// ---------------------------------------------------------------------------
// pool3(avg/max of xt bf16) * sigmoid(act1) -> padded bf16 cat [pos][512]
// Vectorized: 8 channels per thread (uint4 loads/stores).
// ---------------------------------------------------------------------------
__global__ __launch_bounds__(256) void pool_gate_cat(
    const unsigned short* __restrict__ xt, const unsigned short* __restrict__ act1b,
    unsigned short* __restrict__ cat_p)
{
  const int idx = blockIdx.x * 256 + threadIdx.x;   // < NTOT/8
  const int cg = (idx & 31) * 8;
  const int rest = idx >> 5;
  const int p = rest % PPX;
  const int b = rest / PPX;
  const int y = p / 48, x = p - y * 48;
  const unsigned short* base = xt + ((size_t)b * PPX) * 256 + cg;
  float s[8], mx[8];
  #pragma unroll
  for (int e = 0; e < 8; e++) { s[e] = 0.f; mx[e] = -1e30f; }
  #pragma unroll
  for (int dy = -1; dy <= 1; dy++) {
    const int yy = y + dy;
    if (yy < 0 || yy >= 48) continue;
    #pragma unroll
    for (int dx = -1; dx <= 1; dx++) {
      const int xx = x + dx;
      if (xx < 0 || xx >= 48) continue;
      const uint4 d = *(const uint4*)&base[(size_t)(yy * 48 + xx) * 256];
      const unsigned int* dp = (const unsigned int*)&d;
      #pragma unroll
      for (int q = 0; q < 4; q++) {
        const float f0 = bf2f((unsigned short)(dp[q] & 0xffffu));
        const float f1 = bf2f((unsigned short)(dp[q] >> 16));
        s[2 * q] += f0; s[2 * q + 1] += f1;
        mx[2 * q] = fmaxf(mx[2 * q], f0);
        mx[2 * q + 1] = fmaxf(mx[2 * q + 1], f1);
      }
    }
  }
  const uint4 g4 = *(const uint4*)&act1b[((size_t)b * PPX + p) * 256 + cg];
  const unsigned int* gp = (const unsigned int*)&g4;
  unsigned int om[4], oa[4];
  #pragma unroll
  for (int q = 0; q < 4; q++) {
    const float g0 = bf2f((unsigned short)(gp[q] & 0xffffu));
    const float g1 = bf2f((unsigned short)(gp[q] >> 16));
    const float gt0 = 1.f / (1.f + __expf(-g0));
    const float gt1 = 1.f / (1.f + __expf(-g1));
    om[q] = pack2(mx[2 * q] * gt0, mx[2 * q + 1] * gt1);
    oa[q] = pack2(s[2 * q] * (1.f / 9.f) * gt0, s[2 * q + 1] * (1.f / 9.f) * gt1);
  }
  const size_t pp = (size_t)(y + 1) * 50 + (x + 1);
  unsigned short* crow = cat_p + ((size_t)b * PADIMG + pp) * 512 + cg;
  *(uint4*)crow = *(const uint4*)om;
  *(uint4*)(crow + 256) = *(const uint4*)oa;
}

// ---------------------------------------------------------------------------
extern "C" void kernel_launch(void* const* d_in, const int* in_sizes, int n_in,
                              void* d_out, int out_size, void* d_ws, size_t ws_size,
                              hipStream_t stream)
{
  const float* ftr  = (const float*)d_in[0];
  const float* wq   = (const float*)d_in[1];
  const float* bq   = (const float*)d_in[2];
  const float* wk   = (const float*)d_in[3];
  const float* bk   = (const float*)d_in[4];
  const float* wv   = (const float*)d_in[5];
  const float* bv   = (const float*)d_in[6];
  const float* delta= (const float*)d_in[7];
  const float* w1   = (const float*)d_in[8];
  const float* g1   = (const float*)d_in[9];
  const float* b1   = (const float*)d_in[10];
  const float* m1   = (const float*)d_in[11];
  const float* v1   = (const float*)d_in[12];
  const float* w2   = (const float*)d_in[13];
  const float* g2   = (const float*)d_in[14];
  const float* b2   = (const float*)d_in[15];
  const float* m2   = (const float*)d_in[16];
  const float* v2   = (const float*)d_in[17];
  float* out = (float*)d_out;

  // ---- workspace layout (shorts) ----
  const size_t XT = (size_t)NTOT;
  unsigned short* base = (unsigned short*)d_ws;
  unsigned short* xt   = base;
  unsigned short* qt   = xt  + XT;
  unsigned short* kt   = qt  + XT;        // MUST stay qt + NTOT (gemm_qk2 relies on it)
  unsigned short* vbuf = kt  + XT;
  unsigned short* wqb  = vbuf + XT;
  unsigned short* wkb  = wqb + 65536;     // MUST stay wqb + 65536 (contiguous A)
  unsigned short* wvb  = wkb + 65536;
  unsigned short* wr1  = wvb + 65536;
  unsigned short* wr2  = wr1 + (size_t)9 * 256 * 256;
  unsigned short* attn_p = wr2 + (size_t)9 * 256 * 512;        // [b][2500][256]
  unsigned short* act1b  = attn_p + (size_t)NB * PADIMG * 256; // [b][2304][256]
  unsigned short* cat_p  = act1b + XT;                         // [b][2500][512]
  unsigned short* St     = cat_p + (size_t)NB * PADIMG * 512;

  // bqk (512 floats) overlays act1b (unused until conv1)
  float* bqk = (float*)act1b;

  const size_t head_bytes = (size_t)((char*)St - (char*)base);
  const bool modeA = ws_size >= head_bytes + (size_t)NB * PSQ * 2;

  // ---- ONE merged prep launch: casts + biascat + repacks + border clears ----
  prep<<<dim3((PTOT + 255) / 256), 256, 0, stream>>>(
      wq, wk, wv, bq, bk, w1, w2,
      wqb, wkb, wvb, bqk, wr1, wr2, attn_p, cat_p);

  // ---- x transpose ----
  transpose_cast<<<dim3(36, 4, 8), 256, 0, stream>>>(ftr, xt);

  // ---- QKV: merged Q+K (576 blocks), V separate ----
  gemm_qk2<<<dim3(4, 18, 8), 256, 0, stream>>>(wqb, xt, (long)CPb, qt, bqk);
  gemm_nt<2><<<dim3(18, 2, 8), 256, 0, stream>>>(
      xt, (long)CPb, wvb, 0L, 256, vbuf, (long)CPb, PPX, bv);

  if (modeA) {
    gemm_s<<<dim3(18, 18, 8), 256, 0, stream>>>(
        qt, (long)CPb, kt, (long)CPb, St, (long)PSQ, PPX);
    rowstats<<<dim3(PPX, 8), 256, 0, stream>>>(St, (long)PSQ);
    gemm_pv64<<<dim3(2, 36, 8), 256, 0, stream>>>(
        vbuf, (long)CPb, St, (long)PSQ, PPX, attn_p, xt, delta, 0);
  } else {
    for (int b = 0; b < NB; b++) {
      gemm_s<<<dim3(18, 18, 1), 256, 0, stream>>>(
          qt + (size_t)b * CPb, 0L, kt + (size_t)b * CPb, 0L, St, 0L, PPX);
      rowstats<<<dim3(PPX, 1), 256, 0, stream>>>(St, 0L);
      gemm_pv64<<<dim3(2, 36, 1), 256, 0, stream>>>(
          vbuf + (size_t)b * CPb, 0L, St, 0L, PPX, attn_p, xt, delta, b);
    }
  }

  // ---- conv1 + BN + ReLU -> bf16 act1b [p][c] ----
  conv_mfma<true><<<dim3(96, 8), 256, 0, stream>>>(
      attn_p, 256, wr1, g1, b1, m1, v1, (void*)act1b);

  // ---- pool + gate + concat (cat_p borders already cleared in prep) ----
  pool_gate_cat<<<dim3(NTOT / 8 / 256), 256, 0, stream>>>(xt, act1b, cat_p);

  // ---- conv2 + BN + ReLU -> fp32 out ----
  conv_mfma<false><<<dim3(96, 8), 256, 0, stream>>>(
      cat_p, 512, wr2, g2, b2, m2, v2, (void*)out);
}

// Round 17
// 368.647 us; speedup vs baseline: 1.0782x; 1.0045x over previous
//
#include <hip/hip_runtime.h>
#include <math.h>

// Problem constants
#define NB   8
#define CCH  256
#define PPX  2304            // 48*48
#define CPb  (CCH*PPX)       // per-batch C*P = 589824
#define NTOT (NB*CPb)        // 4718592
#define PSQ  (PPX*PPX)       // 5308416
#define PADIMG 2500          // 50*50 padded image

typedef short short8_t __attribute__((ext_vector_type(8)));
typedef float f4_t __attribute__((ext_vector_type(4)));

__device__ __forceinline__ float relu_(float x){ return x > 0.f ? x : 0.f; }

__device__ __forceinline__ unsigned short f2bf(float f) {
  unsigned int u = __builtin_bit_cast(unsigned int, f);
  u += 0x7fffu + ((u >> 16) & 1u);
  return (unsigned short)(u >> 16);
}
__device__ __forceinline__ float bf2f(unsigned short h) {
  unsigned int u = ((unsigned int)h) << 16;
  return __builtin_bit_cast(float, u);
}
__device__ __forceinline__ unsigned int pack2(float a, float b) {
  return (unsigned int)f2bf(a) | ((unsigned int)f2bf(b) << 16);
}

// async global -> LDS, 16B per lane, wave-uniform LDS base (lane spreads x16B)
__device__ __forceinline__ void gll16(const void* g, void* l) {
  __builtin_amdgcn_global_load_lds(
      (const __attribute__((address_space(1))) unsigned int*)g,
      (__attribute__((address_space(3))) unsigned int*)l, 16, 0, 0);
}

// XCD-aware chunked block swizzle (T1): consecutive LOGICAL blocks land on
// the same XCD's L2. Bijective when total%8==0, else identity (ERRATA #11).
__device__ __forceinline__ int swz_lin() {
  const int L = (int)(blockIdx.x + gridDim.x * (blockIdx.y + gridDim.y * blockIdx.z));
  const int total = (int)(gridDim.x * gridDim.y * gridDim.z);
  if ((total & 7) == 0) {
    const int q = total >> 3;
    return (L & 7) * q + (L >> 3);
  }
  return L;
}

// ---------------------------------------------------------------------------
// ONE merged prep kernel: casts, bias concat, weight repacks, border clears,
// PLUS the ftr->xt transpose as a trailing block-range segment.
//   seg0..2: castw wq/wk/wv (65536 each)
//   seg3:    biascat (512)
//   seg4:    repack w1 (Cin=256)   seg5: repack w2 (Cin=512)
//   seg6:    border attn_p         seg7: border cat_p
//   blocks >= PB: transpose_cast (grid (36,4,8) linearized)
// ---------------------------------------------------------------------------
#define PN0 65536
#define PN3 512
#define PN4 (9*256*256)
#define PN5 (9*256*512)
#define PN6 (NB*196*32)
#define PN7 (NB*196*64)
#define POFF1 (PN0)
#define POFF2 (2*PN0)
#define POFF3 (3*PN0)
#define POFF4 (3*PN0 + PN3)
#define POFF5 (POFF4 + PN4)
#define POFF6 (POFF5 + PN5)
#define POFF7 (POFF6 + PN6)
#define PTOT  (POFF7 + PN7)
#define PB    ((PTOT + 255) / 256)
#define TB    (36 * 4 * 8)

__global__ __launch_bounds__(256) void prep(
    const float* __restrict__ wq, const float* __restrict__ wk,
    const float* __restrict__ wv,
    const float* __restrict__ bq, const float* __restrict__ bk,
    const float* __restrict__ w1, const float* __restrict__ w2,
    const float* __restrict__ ftr,
    unsigned short* __restrict__ wqb, unsigned short* __restrict__ wkb,
    unsigned short* __restrict__ wvb, float* __restrict__ bqk,
    unsigned short* __restrict__ wr1, unsigned short* __restrict__ wr2,
    unsigned short* __restrict__ attn_p, unsigned short* __restrict__ cat_p,
    unsigned short* __restrict__ xt)
{
  __shared__ unsigned short T[64][72];
  const int bid = blockIdx.x;
  const int t = threadIdx.x;
  if (bid >= PB) {
    // ---- transpose segment (byte-identical to old transpose_cast) ----
    const int tb = bid - PB;
    const int p0 = (tb % 36) * 64;
    const int c0 = ((tb / 36) % 4) * 64;
    const int b  = tb / 144;
    #pragma unroll
    for (int pass = 0; pass < 4; pass++) {
      const int cr = pass * 16 + (t >> 4);
      const int pc = (t & 15) * 4;
      float4 v = *(const float4*)&ftr[((size_t)(b * 256 + c0 + cr)) * PPX + p0 + pc];
      T[pc + 0][cr] = f2bf(v.x); T[pc + 1][cr] = f2bf(v.y);
      T[pc + 2][cr] = f2bf(v.z); T[pc + 3][cr] = f2bf(v.w);
    }
    __syncthreads();
    #pragma unroll
    for (int pass = 0; pass < 2; pass++) {
      const int pr = pass * 32 + (t >> 3);
      const int cc = (t & 7) * 8;
      *(uint4*)&xt[((size_t)(b * PPX + p0 + pr)) * 256 + c0 + cc] = *(const uint4*)&T[pr][cc];
    }
    return;
  }
  int idx = bid * 256 + t;
  if (idx >= PTOT) return;
  if (idx < POFF1) { wqb[idx] = f2bf(wq[idx]); return; }
  if (idx < POFF2) { const int i = idx - POFF1; wkb[i] = f2bf(wk[i]); return; }
  if (idx < POFF3) { const int i = idx - POFF2; wvb[i] = f2bf(wv[i]); return; }
  if (idx < POFF4) {
    const int i = idx - POFF3;
    bqk[i] = (i < 256) ? bq[i] : bk[i - 256];
    return;
  }
  if (idx < POFF5) {
    const int i = idx - POFF4;               // repack w1, Cin=256
    const int c = i % 256;
    const int rest = i / 256;
    const int o = rest % 256;
    const int tap = rest / 256;
    wr1[i] = f2bf(w1[((size_t)o * 256 + c) * 9 + tap]);
    return;
  }
  if (idx < POFF6) {
    const int i = idx - POFF5;               // repack w2, Cin=512
    const int c = i % 512;
    const int rest = i / 512;
    const int o = rest % 256;
    const int tap = rest / 256;
    wr2[i] = f2bf(w2[((size_t)o * 512 + c) * 9 + tap]);
    return;
  }
  // border clears (uint4 granularity)
  unsigned short* p;
  int C, r;
  if (idx < POFF7) { p = attn_p; C = 256; r = idx - POFF6; }
  else             { p = cat_p;  C = 512; r = idx - POFF7; }
  const int v4 = C >> 3;
  const int perB = 196 * v4;
  const int b = r / perB;
  const int rr = r - b * perB;
  const int pos = rr / v4;
  const int co = (rr - pos * v4) * 8;
  int pp;
  if (pos < 50)        pp = pos;                                   // row 0
  else if (pos < 100)  pp = 2450 + (pos - 50);                     // row 49
  else { const int j = pos - 100; pp = (1 + (j >> 1)) * 50 + (j & 1) * 49; }
  uint4 z; z.x = 0; z.y = 0; z.z = 0; z.w = 0;
  *(uint4*)(p + ((size_t)b * PADIMG + pp) * C + co) = z;
}

// ---------------------------------------------------------------------------
// Generic bf16 MFMA GEMM: O[n][m] = sum_k A[m][k]*B[n][k]
// Tile 128x128, 4 waves (2x2 of 64x64). Round-3 proven schedule.
// EPI: 2 bias on n (V gemm only)
// ---------------------------------------------------------------------------
template<int EPI>
__global__ __launch_bounds__(256) void gemm_nt(
    const unsigned short* __restrict__ A, long Ab,
    const unsigned short* __restrict__ B, long Bb, int K,
    unsigned short* __restrict__ O, long Ob, int ldo,
    const float* __restrict__ bias)
{
  const int t = threadIdx.x;
  const int ln = t & 63;
  const int wid = t >> 6;
  const int wm = (wid & 1) * 64, wn = (wid >> 1) * 64;
  const int lm = ln & 15, lg = ln >> 4;
  const int m0 = blockIdx.x * 128, n0 = blockIdx.y * 128;
  const long bz = blockIdx.z;
  const unsigned short* Ap = A + bz * Ab;
  const unsigned short* Bp = B + bz * Bb;

  __shared__ __align__(16) unsigned short As[128 * 32];
  __shared__ __align__(16) unsigned short Bs[128 * 32];

  const int sR = ln >> 2, sP = ln & 3;
  const int fbase = lm * 32 + (((lg + (lm >> 2)) & 3) * 8);

  f4_t acc[4][4];
  #pragma unroll
  for (int i = 0; i < 4; i++)
    #pragma unroll
    for (int j = 0; j < 4; j++) acc[i][j] = (f4_t){0.f, 0.f, 0.f, 0.f};

  for (int k0 = 0; k0 < K; k0 += 32) {
    __syncthreads();
    #pragma unroll
    for (int i = wid; i < 8; i += 4) {
      const int R = i * 16 + sR;
      const int l = (sP - (R >> 2)) & 3;              // logical chan-group
      gll16(Ap + (size_t)(m0 + R) * K + k0 + l * 8, As + i * 512);
      gll16(Bp + (size_t)(n0 + R) * K + k0 + l * 8, Bs + i * 512);
    }
    __syncthreads();
    short8_t a[4], b[4];
    #pragma unroll
    for (int ti = 0; ti < 4; ti++)
      a[ti] = *(const short8_t*)(As + (wm + ti * 16) * 32 + fbase);
    #pragma unroll
    for (int tj = 0; tj < 4; tj++)
      b[tj] = *(const short8_t*)(Bs + (wn + tj * 16) * 32 + fbase);
    #pragma unroll
    for (int ti = 0; ti < 4; ti++)
      #pragma unroll
      for (int tj = 0; tj < 4; tj++)
        acc[ti][tj] = __builtin_amdgcn_mfma_f32_16x16x32_bf16(
            a[ti], b[tj], acc[ti][tj], 0, 0, 0);
  }

  #pragma unroll
  for (int ti = 0; ti < 4; ti++) {
    const int mb = m0 + wm + ti * 16 + (lg << 2);
    #pragma unroll
    for (int tj = 0; tj < 4; tj++) {
      const int n = n0 + wn + tj * 16 + lm;
      float add0 = 0.f, add1 = 0.f, add2 = 0.f, add3 = 0.f;
      if (EPI == 2) { add0 = add1 = add2 = add3 = bias[n]; }
      uint2 o;
      o.x = pack2(acc[ti][tj][0] + add0, acc[ti][tj][1] + add1);
      o.y = pack2(acc[ti][tj][2] + add2, acc[ti][tj][3] + add3);
      *(uint2*)(O + bz * Ob + (size_t)n * ldo + mb) = o;
    }
  }
}

// ---------------------------------------------------------------------------
// QK^T GEMM, tile 128x128, BK=64: two 32-chan sub-slices staged per barrier,
// 32 MFMA per wave per iteration, 36 barriers. 32 KB LDS, acc 4x4.
// XCD-swizzled block order.
// ---------------------------------------------------------------------------
__global__ __launch_bounds__(256) void gemm_s(
    const unsigned short* __restrict__ A, long Ab,
    const unsigned short* __restrict__ B, long Bb,
    unsigned short* __restrict__ O, long Ob, int ldo)
{
  const int K = 256;
  const int t = threadIdx.x;
  const int ln = t & 63;
  const int wid = t >> 6;
  const int wm = (wid & 1) * 64, wn = (wid >> 1) * 64;
  const int lm = ln & 15, lg = ln >> 4;

  const int lin = swz_lin();
  const int lx = lin % (int)gridDim.x;
  const int rest = lin / (int)gridDim.x;
  const int ly = rest % (int)gridDim.y;
  const int lz = rest / (int)gridDim.y;

  const int m0 = lx * 128, n0 = ly * 128;
  const long bz = lz;
  const unsigned short* Ap = A + bz * Ab;
  const unsigned short* Bp = B + bz * Bb;

  __shared__ __align__(16) unsigned short As[2][128 * 32];
  __shared__ __align__(16) unsigned short Bs[2][128 * 32];

  const int sR = ln >> 2, sP = ln & 3;
  const int fbase = lm * 32 + (((lg + (lm >> 2)) & 3) * 8);

  f4_t acc[4][4];
  #pragma unroll
  for (int i = 0; i < 4; i++)
    #pragma unroll
    for (int j = 0; j < 4; j++) acc[i][j] = (f4_t){0.f, 0.f, 0.f, 0.f};

  for (int k0 = 0; k0 < K; k0 += 64) {
    __syncthreads();
    #pragma unroll
    for (int s = 0; s < 2; s++) {
      #pragma unroll
      for (int i = wid; i < 8; i += 4) {
        const int R = i * 16 + sR;
        const int l = (sP - (R >> 2)) & 3;
        gll16(Ap + (size_t)(m0 + R) * K + k0 + s * 32 + l * 8, &As[s][i * 512]);
        gll16(Bp + (size_t)(n0 + R) * K + k0 + s * 32 + l * 8, &Bs[s][i * 512]);
      }
    }
    __syncthreads();
    #pragma unroll
    for (int s = 0; s < 2; s++) {
      short8_t a[4], b[4];
      #pragma unroll
      for (int ti = 0; ti < 4; ti++)
        a[ti] = *(const short8_t*)(&As[s][(wm + ti * 16) * 32 + fbase]);
      #pragma unroll
      for (int tj = 0; tj < 4; tj++)
        b[tj] = *(const short8_t*)(&Bs[s][(wn + tj * 16) * 32 + fbase]);
      #pragma unroll
      for (int ti = 0; ti < 4; ti++)
        #pragma unroll
        for (int tj = 0; tj < 4; tj++)
          acc[ti][tj] = __builtin_amdgcn_mfma_f32_16x16x32_bf16(
              a[ti], b[tj], acc[ti][tj], 0, 0, 0);
    }
  }

  #pragma unroll
  for (int ti = 0; ti < 4; ti++) {
    const int mb = m0 + wm + ti * 16 + (lg << 2);
    #pragma unroll
    for (int tj = 0; tj < 4; tj++) {
      const int n = n0 + wn + tj * 16 + lm;
      uint2 o;
      o.x = pack2(acc[ti][tj][0], acc[ti][tj][1]);
      o.y = pack2(acc[ti][tj][2], acc[ti][tj][3]);
      *(uint2*)(O + bz * Ob + (size_t)n * ldo + mb) = o;
    }
  }
}

// ---------------------------------------------------------------------------
// Merged Q+K GEMM (standalone clone of gemm_nt): A = wqb||wkb [512][256],
// B = xt. Rows 0..255 -> qt, 256..511 -> kt (= qt + NTOT).
// ---------------------------------------------------------------------------
__global__ __launch_bounds__(256) void gemm_qk2(
    const unsigned short* __restrict__ A,
    const unsigned short* __restrict__ B, long Bb,
    unsigned short* __restrict__ Oq,
    const float* __restrict__ bias)
{
  const int t = threadIdx.x;
  const int ln = t & 63;
  const int wid = t >> 6;
  const int wm = (wid & 1) * 64, wn = (wid >> 1) * 64;
  const int lm = ln & 15, lg = ln >> 4;
  const int m0 = blockIdx.x * 128, n0 = blockIdx.y * 128;
  const long bz = blockIdx.z;
  const int K = 256;
  const unsigned short* Ap = A;
  const unsigned short* Bp = B + bz * Bb;

  __shared__ __align__(16) unsigned short As[128 * 32];
  __shared__ __align__(16) unsigned short Bs[128 * 32];

  const int sR = ln >> 2, sP = ln & 3;
  const int fbase = lm * 32 + (((lg + (lm >> 2)) & 3) * 8);

  f4_t acc[4][4];
  #pragma unroll
  for (int i = 0; i < 4; i++)
    #pragma unroll
    for (int j = 0; j < 4; j++) acc[i][j] = (f4_t){0.f, 0.f, 0.f, 0.f};

  for (int k0 = 0; k0 < K; k0 += 32) {
    __syncthreads();
    #pragma unroll
    for (int i = wid; i < 8; i += 4) {
      const int R = i * 16 + sR;
      const int l = (sP - (R >> 2)) & 3;
      gll16(Ap + (size_t)(m0 + R) * K + k0 + l * 8, As + i * 512);
      gll16(Bp + (size_t)(n0 + R) * K + k0 + l * 8, Bs + i * 512);
    }
    __syncthreads();
    short8_t a[4], b[4];
    #pragma unroll
    for (int ti = 0; ti < 4; ti++)
      a[ti] = *(const short8_t*)(As + (wm + ti * 16) * 32 + fbase);
    #pragma unroll
    for (int tj = 0; tj < 4; tj++)
      b[tj] = *(const short8_t*)(Bs + (wn + tj * 16) * 32 + fbase);
    #pragma unroll
    for (int ti = 0; ti < 4; ti++)
      #pragma unroll
      for (int tj = 0; tj < 4; tj++)
        acc[ti][tj] = __builtin_amdgcn_mfma_f32_16x16x32_bf16(
            a[ti], b[tj], acc[ti][tj], 0, 0, 0);
  }

  #pragma unroll
  for (int ti = 0; ti < 4; ti++) {
    const int mb = m0 + wm + ti * 16 + (lg << 2);     // 0..511, wave-uniform split
    const size_t obase = (mb >= 256 ? (size_t)NTOT : 0) + (size_t)bz * CPb;
    const int mc = mb & 255;
    #pragma unroll
    for (int tj = 0; tj < 4; tj++) {
      const int n = n0 + wn + tj * 16 + lm;
      uint2 o;
      o.x = pack2(acc[ti][tj][0] + bias[mb],     acc[ti][tj][1] + bias[mb + 1]);
      o.y = pack2(acc[ti][tj][2] + bias[mb + 2], acc[ti][tj][3] + bias[mb + 3]);
      *(uint2*)(Oq + obase + (size_t)n * 256 + mc) = o;
    }
  }
}

// ---------------------------------------------------------------------------
// PV GEMM: tile 128(M=chan) x 64(N=pixel), 4 waves 2x2 (each 64x32, acc 4x2).
// BK=32, 12 KB LDS, XCD-swizzled (St x-pair shares one XCD's L2).
// Epilogue: out = delta*acc + x (bf16 from xt, coalesced) -> attn_p [pos][256].
// ---------------------------------------------------------------------------
__global__ __launch_bounds__(256) void gemm_pv64(
    const unsigned short* __restrict__ A, long Ab,   // vbuf [c][i]
    const unsigned short* __restrict__ B, long Bb,   // St weights [j][i]
    int K,
    unsigned short* __restrict__ O,                  // attn_p
    const unsigned short* __restrict__ X,            // xt [b][p][c] bf16
    const float* __restrict__ delta, int bstart)
{
  const int t = threadIdx.x;
  const int ln = t & 63;
  const int wid = t >> 6;
  const int wm = (wid & 1) * 64, wn = (wid >> 1) * 32;
  const int lm = ln & 15, lg = ln >> 4;

  const int lin = swz_lin();
  const int lx = lin % (int)gridDim.x;
  const int rest = lin / (int)gridDim.x;
  const int ly = rest % (int)gridDim.y;
  const int lz = rest / (int)gridDim.y;

  const int m0 = lx * 128, n0 = ly * 64;
  const long bz = lz;
  const int b = bstart + (int)bz;
  const unsigned short* Ap = A + bz * Ab;
  const unsigned short* Bp = B + bz * Bb;

  __shared__ __align__(16) unsigned short As[128 * 32];
  __shared__ __align__(16) unsigned short Bs[64 * 32];

  const int sR = ln >> 2, sP = ln & 3;
  const int fbase = lm * 32 + (((lg + (lm >> 2)) & 3) * 8);

  f4_t acc[4][2];
  #pragma unroll
  for (int i = 0; i < 4; i++)
    #pragma unroll
    for (int j = 0; j < 2; j++) acc[i][j] = (f4_t){0.f, 0.f, 0.f, 0.f};

  for (int k0 = 0; k0 < K; k0 += 32) {
    __syncthreads();
    #pragma unroll
    for (int i = wid; i < 8; i += 4) {
      const int R = i * 16 + sR;
      const int l = (sP - (R >> 2)) & 3;
      gll16(Ap + (size_t)(m0 + R) * K + k0 + l * 8, As + i * 512);
    }
    {
      const int R = wid * 16 + sR;                    // 4 chunks, 1 per wave
      const int l = (sP - (R >> 2)) & 3;
      gll16(Bp + (size_t)(n0 + R) * K + k0 + l * 8, Bs + wid * 512);
    }
    __syncthreads();
    short8_t a[4], b8[2];
    #pragma unroll
    for (int ti = 0; ti < 4; ti++)
      a[ti] = *(const short8_t*)(As + (wm + ti * 16) * 32 + fbase);
    #pragma unroll
    for (int tj = 0; tj < 2; tj++)
      b8[tj] = *(const short8_t*)(Bs + (wn + tj * 16) * 32 + fbase);
    #pragma unroll
    for (int ti = 0; ti < 4; ti++)
      #pragma unroll
      for (int tj = 0; tj < 2; tj++)
        acc[ti][tj] = __builtin_amdgcn_mfma_f32_16x16x32_bf16(
            a[ti], b8[tj], acc[ti][tj], 0, 0, 0);
  }

  const float d0 = delta[0];
  #pragma unroll
  for (int ti = 0; ti < 4; ti++) {
    const int mb = m0 + wm + ti * 16 + (lg << 2);     // channel c
    #pragma unroll
    for (int tj = 0; tj < 2; tj++) {
      const int n = n0 + wn + tj * 16 + lm;            // pixel j
      const int y = n / 48, x = n - (n / 48) * 48;
      const size_t pp = (size_t)(y + 1) * 50 + (x + 1);
      const uint2 xv = *(const uint2*)(X + ((size_t)b * PPX + n) * 256 + mb);
      float fr[4];
      fr[0] = bf2f((unsigned short)(xv.x & 0xffffu));
      fr[1] = bf2f((unsigned short)(xv.x >> 16));
      fr[2] = bf2f((unsigned short)(xv.y & 0xffffu));
      fr[3] = bf2f((unsigned short)(xv.y >> 16));
      float vr[4];
      #pragma unroll
      for (int r = 0; r < 4; r++)
        vr[r] = d0 * acc[ti][tj][r] + fr[r];
      uint2 o;
      o.x = pack2(vr[0], vr[1]);
      o.y = pack2(vr[2], vr[3]);
      *(uint2*)(O + ((size_t)b * PADIMG + pp) * 256 + mb) = o;
    }
  }
}

// ---------------------------------------------------------------------------
// Row softmax of St IN PLACE: row j: W[i] = exp(s-mx)/sum  (bf16 out)
// ---------------------------------------------------------------------------
__global__ __launch_bounds__(256) void rowstats(
    unsigned short* __restrict__ St, long sstride)
{
  const int j = blockIdx.x, bb = blockIdx.y;
  unsigned short* row = St + (long)bb * sstride + (size_t)j * PPX;
  const int t = threadIdx.x;

  float v[16];
  int nv = 0;
  float m = -1e30f;
  for (int ch = t; ch < 288; ch += 256) {
    const uint4 d = *(const uint4*)(row + ch * 8);
    const unsigned int* dp = (const unsigned int*)&d;
    #pragma unroll
    for (int q = 0; q < 4; q++) {
      v[nv]     = bf2f((unsigned short)(dp[q] & 0xffffu));
      v[nv + 1] = bf2f((unsigned short)(dp[q] >> 16));
      m = fmaxf(m, fmaxf(v[nv], v[nv + 1]));
      nv += 2;
    }
  }
  #pragma unroll
  for (int off = 32; off > 0; off >>= 1)
    m = fmaxf(m, __shfl_xor(m, off));
  __shared__ float red[8];
  if ((t & 63) == 0) red[t >> 6] = m;
  __syncthreads();
  m = fmaxf(fmaxf(red[0], red[1]), fmaxf(red[2], red[3]));

  float sum = 0.f;
  for (int u = 0; u < nv; u++) { v[u] = __expf(v[u] - m); sum += v[u]; }
  #pragma unroll
  for (int off = 32; off > 0; off >>= 1)
    sum += __shfl_xor(sum, off);
  if ((t & 63) == 0) red[4 + (t >> 6)] = sum;
  __syncthreads();
  const float inv = 1.f / (red[4] + red[5] + red[6] + red[7]);

  int u = 0;
  for (int ch = t; ch < 288; ch += 256) {
    unsigned int res[4];
    #pragma unroll
    for (int q = 0; q < 4; q++) {
      res[q] = pack2(v[u] * inv, v[u + 1] * inv);
      u += 2;
    }
    *(uint4*)(row + ch * 8) = *(const uint4*)res;
  }
}

// ---------------------------------------------------------------------------
// Conv3x3 + BN + ReLU, MFMA bf16, [pos][chan] activations, async LDS staging.
// 256 thr (4 waves), tile 32 Cout x 192 px. Grid = 768 blocks = 3/CU.
// FUSE_POOL (conv1): epilogue computes gate=sigmoid(bf16(act1)) in-register
// and writes pooled xt (max & avg) * gate directly to cat_p [pos][512] --
// deletes the separate pool kernel and the act1b round-trip. Bit-identical
// ordering to the old pool_gate_cat (dy-major/dx-minor, same pack order).
// ---------------------------------------------------------------------------
template<bool FUSE_POOL>
__global__ __launch_bounds__(256) void conv_mfma(
    const unsigned short* __restrict__ act_p, int Cin,
    const unsigned short* __restrict__ wr,
    const float* __restrict__ gamma, const float* __restrict__ beta,
    const float* __restrict__ mean,  const float* __restrict__ var,
    void* __restrict__ outv, const unsigned short* __restrict__ xtp)
{
  const int t  = threadIdx.x;
  const int wv = t >> 6;          // wave 0..3 -> 48-px chunk
  const int ln = t & 63;
  const int lm = ln & 15;
  const int lg = ln >> 4;

  const int bx = blockIdx.x;      // 96 = 8 images * 12 pixel-tiles (192 px)
  const int bb = bx / 12;
  const int p0 = (bx % 12) * 192;
  const int m0 = blockIdx.y * 32; // 8 m-tiles of 32 Cout

  __shared__ __align__(16) unsigned short As[9 * 32 * 32]; // [tap][m][c] 18.4 KB
  __shared__ __align__(16) unsigned short Bs[304 * 32];    // [pos][c]    19.5 KB

  const int qbase = p0 + 2 * (p0 / 48);    // q(p0) - 51
  int qoff[3];
  #pragma unroll
  for (int tj = 0; tj < 3; tj++) {
    const int p = p0 + wv * 48 + tj * 16 + lm;
    qoff[tj] = (p - p0) + 2 * (p / 48 - p0 / 48) + 51;
  }

  const int sR = ln >> 2, sP = ln & 3;
  const int sl = (sP - (sR >> 2)) & 3;
  const int abase = lm * 32 + (((lg + (lm >> 2)) & 3) * 8);

  const unsigned short* gb = act_p + (size_t)bb * PADIMG * Cin + sl * 8;

  f4_t acc[2][3];
  #pragma unroll
  for (int i = 0; i < 2; i++)
    #pragma unroll
    for (int j = 0; j < 3; j++) acc[i][j] = (f4_t){0.f, 0.f, 0.f, 0.f};

  for (int c0 = 0; c0 < Cin; c0 += 32) {
    __syncthreads();
    for (int i = wv; i < 18; i += 4) {
      const int R = i * 16 + sR;                          // 0..287
      const int tap = R >> 5, mr = R & 31;
      const int l = (sP - (R >> 2)) & 3;
      gll16(wr + ((size_t)(tap * 256 + m0 + mr)) * Cin + c0 + l * 8, As + i * 512);
    }
    for (int i = wv; i < 19; i += 4) {
      const int R = i * 16 + sR;                          // 0..303
      int Rg = qbase + R;
      if (Rg > PADIMG - 1) Rg = PADIMG - 1;
      gll16(gb + (size_t)Rg * Cin + c0, Bs + i * 512);
    }
    __syncthreads();
    #pragma unroll
    for (int ky = 0; ky < 3; ky++) {
      #pragma unroll
      for (int kx = 0; kx < 3; kx++) {
        const int off = (ky - 1) * 50 + (kx - 1);
        const int tap = ky * 3 + kx;
        short8_t a[2], b[3];
        #pragma unroll
        for (int ti = 0; ti < 2; ti++)
          a[ti] = *(const short8_t*)(As + tap * 1024 + ti * 512 + abase);
        #pragma unroll
        for (int tj = 0; tj < 3; tj++) {
          const int R = qoff[tj] + off;
          const int slot = (lg + (R >> 2)) & 3;
          b[tj] = *(const short8_t*)(Bs + R * 32 + slot * 8);
        }
        #pragma unroll
        for (int ti = 0; ti < 2; ti++)
          #pragma unroll
          for (int tj = 0; tj < 3; tj++)
            acc[ti][tj] = __builtin_amdgcn_mfma_f32_16x16x32_bf16(
                a[ti], b[tj], acc[ti][tj], 0, 0, 0);
      }
    }
  }

  // ---- epilogue: BN + ReLU (+ fused pool/gate/cat for conv1) ----
  #pragma unroll
  for (int ti = 0; ti < 2; ti++) {
    const int m = m0 + ti * 16 + (lg << 2);
    float inv[4], add[4];
    #pragma unroll
    for (int r = 0; r < 4; r++) {
      inv[r] = gamma[m + r] * rsqrtf(var[m + r] + 1e-5f);
      add[r] = beta[m + r] - mean[m + r] * inv[r];
    }
    #pragma unroll
    for (int tj = 0; tj < 3; tj++) {
      const int p = p0 + wv * 48 + tj * 16 + lm;
      float vr[4];
      #pragma unroll
      for (int r = 0; r < 4; r++)
        vr[r] = relu_(acc[ti][tj][r] * inv[r] + add[r]);
      if (FUSE_POOL) {
        const int y = p / 48, x = p - y * 48;
        // gate from bf16-rounded act1 (matches old act1b store/load)
        float gt[4];
        #pragma unroll
        for (int r = 0; r < 4; r++) {
          const float a1 = bf2f(f2bf(vr[r]));
          gt[r] = 1.f / (1.f + __expf(-a1));
        }
        // pool xt 3x3 (dy-major, dx-minor; identical accumulation order)
        float s[4], mx[4];
        #pragma unroll
        for (int r = 0; r < 4; r++) { s[r] = 0.f; mx[r] = -1e30f; }
        #pragma unroll
        for (int dy = -1; dy <= 1; dy++) {
          const int yy = y + dy;
          if (yy < 0 || yy >= 48) continue;
          #pragma unroll
          for (int dx = -1; dx <= 1; dx++) {
            const int xx = x + dx;
            if (xx < 0 || xx >= 48) continue;
            const uint2 xv = *(const uint2*)(xtp +
                ((size_t)(bb * PPX + yy * 48 + xx)) * 256 + m);
            float f0 = bf2f((unsigned short)(xv.x & 0xffffu));
            float f1 = bf2f((unsigned short)(xv.x >> 16));
            float f2 = bf2f((unsigned short)(xv.y & 0xffffu));
            float f3 = bf2f((unsigned short)(xv.y >> 16));
            s[0] += f0; s[1] += f1; s[2] += f2; s[3] += f3;
            mx[0] = fmaxf(mx[0], f0); mx[1] = fmaxf(mx[1], f1);
            mx[2] = fmaxf(mx[2], f2); mx[3] = fmaxf(mx[3], f3);
          }
        }
        const size_t pp = (size_t)(y + 1) * 50 + (x + 1);
        unsigned short* crow = (unsigned short*)outv +
            ((size_t)bb * PADIMG + pp) * 512 + m;
        uint2 om, oa;
        om.x = pack2(mx[0] * gt[0], mx[1] * gt[1]);
        om.y = pack2(mx[2] * gt[2], mx[3] * gt[3]);
        oa.x = pack2(s[0] * (1.f / 9.f) * gt[0], s[1] * (1.f / 9.f) * gt[1]);
        oa.y = pack2(s[2] * (1.f / 9.f) * gt[2], s[3] * (1.f / 9.f) * gt[3]);
        *(uint2*)crow = om;
        *(uint2*)(crow + 256) = oa;
      } else {
        #pragma unroll
        for (int r = 0; r < 4; r++)
          ((float*)outv)[((size_t)(bb * 256 + m + r)) * PPX + p] = vr[r];
      }
    }
  }
}

// ---------------------------------------------------------------------------
extern "C" void kernel_launch(void* const* d_in, const int* in_sizes, int n_in,
                              void* d_out, int out_size, void* d_ws, size_t ws_size,
                              hipStream_t stream)
{
  const float* ftr  = (const float*)d_in[0];
  const float* wq   = (const float*)d_in[1];
  const float* bq   = (const float*)d_in[2];
  const float* wk   = (const float*)d_in[3];
  const float* bk   = (const float*)d_in[4];
  const float* wv   = (const float*)d_in[5];
  const float* bv   = (const float*)d_in[6];
  const float* delta= (const float*)d_in[7];
  const float* w1   = (const float*)d_in[8];
  const float* g1   = (const float*)d_in[9];
  const float* b1   = (const float*)d_in[10];
  const float* m1   = (const float*)d_in[11];
  const float* v1   = (const float*)d_in[12];
  const float* w2   = (const float*)d_in[13];
  const float* g2   = (const float*)d_in[14];
  const float* b2   = (const float*)d_in[15];
  const float* m2   = (const float*)d_in[16];
  const float* v2   = (const float*)d_in[17];
  float* out = (float*)d_out;

  // ---- workspace layout (shorts) ----
  const size_t XT = (size_t)NTOT;
  unsigned short* base = (unsigned short*)d_ws;
  unsigned short* xt   = base;
  unsigned short* qt   = xt  + XT;
  unsigned short* kt   = qt  + XT;        // MUST stay qt + NTOT (gemm_qk2 relies on it)
  unsigned short* vbuf = kt  + XT;
  unsigned short* wqb  = vbuf + XT;
  unsigned short* wkb  = wqb + 65536;     // MUST stay wqb + 65536 (contiguous A)
  unsigned short* wvb  = wkb + 65536;
  unsigned short* wr1  = wvb + 65536;
  unsigned short* wr2  = wr1 + (size_t)9 * 256 * 256;
  unsigned short* attn_p = wr2 + (size_t)9 * 256 * 512;        // [b][2500][256]
  unsigned short* act1b  = attn_p + (size_t)NB * PADIMG * 256; // bqk overlay region
  unsigned short* cat_p  = act1b + XT;                         // [b][2500][512]
  unsigned short* St     = cat_p + (size_t)NB * PADIMG * 512;

  // bqk (512 floats) overlays act1b region (otherwise unused now)
  float* bqk = (float*)act1b;

  const size_t head_bytes = (size_t)((char*)St - (char*)base);
  const bool modeA = ws_size >= head_bytes + (size_t)NB * PSQ * 2;

  // ---- ONE merged prep launch: casts+biascat+repacks+borders+transpose ----
  prep<<<dim3(PB + TB), 256, 0, stream>>>(
      wq, wk, wv, bq, bk, w1, w2, ftr,
      wqb, wkb, wvb, bqk, wr1, wr2, attn_p, cat_p, xt);

  // ---- QKV: merged Q+K (576 blocks), V separate ----
  gemm_qk2<<<dim3(4, 18, 8), 256, 0, stream>>>(wqb, xt, (long)CPb, qt, bqk);
  gemm_nt<2><<<dim3(18, 2, 8), 256, 0, stream>>>(
      xt, (long)CPb, wvb, 0L, 256, vbuf, (long)CPb, PPX, bv);

  if (modeA) {
    gemm_s<<<dim3(18, 18, 8), 256, 0, stream>>>(
        qt, (long)CPb, kt, (long)CPb, St, (long)PSQ, PPX);
    rowstats<<<dim3(PPX, 8), 256, 0, stream>>>(St, (long)PSQ);
    gemm_pv64<<<dim3(2, 36, 8), 256, 0, stream>>>(
        vbuf, (long)CPb, St, (long)PSQ, PPX, attn_p, xt, delta, 0);
  } else {
    for (int b = 0; b < NB; b++) {
      gemm_s<<<dim3(18, 18, 1), 256, 0, stream>>>(
          qt + (size_t)b * CPb, 0L, kt + (size_t)b * CPb, 0L, St, 0L, PPX);
      rowstats<<<dim3(PPX, 1), 256, 0, stream>>>(St, 0L);
      gemm_pv64<<<dim3(2, 36, 1), 256, 0, stream>>>(
          vbuf + (size_t)b * CPb, 0L, St, 0L, PPX, attn_p, xt, delta, b);
    }
  }

  // ---- conv1 + BN + ReLU + FUSED pool/gate/cat -> cat_p [pos][512] ----
  conv_mfma<true><<<dim3(96, 8), 256, 0, stream>>>(
      attn_p, 256, wr1, g1, b1, m1, v1, (void*)cat_p, xt);

  // ---- conv2 + BN + ReLU -> fp32 out ----
  conv_mfma<false><<<dim3(96, 8), 256, 0, stream>>>(
      cat_p, 512, wr2, g2, b2, m2, v2, (void*)out, nullptr);
}

// Round 18
// 368.644 us; speedup vs baseline: 1.0782x; 1.0000x over previous
//
#include <hip/hip_runtime.h>
#include <math.h>

// Problem constants
#define NB   8
#define CCH  256
#define PPX  2304            // 48*48
#define CPb  (CCH*PPX)       // per-batch C*P = 589824
#define NTOT (NB*CPb)        // 4718592
#define PSQ  (PPX*PPX)       // 5308416
#define PADIMG 2500          // 50*50 padded image

typedef short short8_t __attribute__((ext_vector_type(8)));
typedef float f4_t __attribute__((ext_vector_type(4)));

__device__ __forceinline__ float relu_(float x){ return x > 0.f ? x : 0.f; }

__device__ __forceinline__ unsigned short f2bf(float f) {
  unsigned int u = __builtin_bit_cast(unsigned int, f);
  u += 0x7fffu + ((u >> 16) & 1u);
  return (unsigned short)(u >> 16);
}
__device__ __forceinline__ float bf2f(unsigned short h) {
  unsigned int u = ((unsigned int)h) << 16;
  return __builtin_bit_cast(float, u);
}
__device__ __forceinline__ unsigned int pack2(float a, float b) {
  return (unsigned int)f2bf(a) | ((unsigned int)f2bf(b) << 16);
}

// async global -> LDS, 16B per lane, wave-uniform LDS base (lane spreads x16B)
__device__ __forceinline__ void gll16(const void* g, void* l) {
  __builtin_amdgcn_global_load_lds(
      (const __attribute__((address_space(1))) unsigned int*)g,
      (__attribute__((address_space(3))) unsigned int*)l, 16, 0, 0);
}

// XCD-aware chunked block swizzle (T1): consecutive LOGICAL blocks land on
// the same XCD's L2. Bijective when total%8==0, else identity (ERRATA #11).
__device__ __forceinline__ int swz_lin() {
  const int L = (int)(blockIdx.x + gridDim.x * (blockIdx.y + gridDim.y * blockIdx.z));
  const int total = (int)(gridDim.x * gridDim.y * gridDim.z);
  if ((total & 7) == 0) {
    const int q = total >> 3;
    return (L & 7) * q + (L >> 3);
  }
  return L;
}

// ---------------------------------------------------------------------------
// ONE merged prep kernel: casts, bias concat, weight repacks, border clears,
// PLUS the ftr->xt transpose as a trailing block-range segment.
// ---------------------------------------------------------------------------
#define PN0 65536
#define PN3 512
#define PN4 (9*256*256)
#define PN5 (9*256*512)
#define PN6 (NB*196*32)
#define PN7 (NB*196*64)
#define POFF1 (PN0)
#define POFF2 (2*PN0)
#define POFF3 (3*PN0)
#define POFF4 (3*PN0 + PN3)
#define POFF5 (POFF4 + PN4)
#define POFF6 (POFF5 + PN5)
#define POFF7 (POFF6 + PN6)
#define PTOT  (POFF7 + PN7)
#define PB    ((PTOT + 255) / 256)
#define TB    (36 * 4 * 8)

__global__ __launch_bounds__(256) void prep(
    const float* __restrict__ wq, const float* __restrict__ wk,
    const float* __restrict__ wv,
    const float* __restrict__ bq, const float* __restrict__ bk,
    const float* __restrict__ w1, const float* __restrict__ w2,
    const float* __restrict__ ftr,
    unsigned short* __restrict__ wqb, unsigned short* __restrict__ wkb,
    unsigned short* __restrict__ wvb, float* __restrict__ bqk,
    unsigned short* __restrict__ wr1, unsigned short* __restrict__ wr2,
    unsigned short* __restrict__ attn_p, unsigned short* __restrict__ cat_p,
    unsigned short* __restrict__ xt)
{
  __shared__ unsigned short T[64][72];
  const int bid = blockIdx.x;
  const int t = threadIdx.x;
  if (bid >= PB) {
    // ---- transpose segment (byte-identical to old transpose_cast) ----
    const int tb = bid - PB;
    const int p0 = (tb % 36) * 64;
    const int c0 = ((tb / 36) % 4) * 64;
    const int b  = tb / 144;
    #pragma unroll
    for (int pass = 0; pass < 4; pass++) {
      const int cr = pass * 16 + (t >> 4);
      const int pc = (t & 15) * 4;
      float4 v = *(const float4*)&ftr[((size_t)(b * 256 + c0 + cr)) * PPX + p0 + pc];
      T[pc + 0][cr] = f2bf(v.x); T[pc + 1][cr] = f2bf(v.y);
      T[pc + 2][cr] = f2bf(v.z); T[pc + 3][cr] = f2bf(v.w);
    }
    __syncthreads();
    #pragma unroll
    for (int pass = 0; pass < 2; pass++) {
      const int pr = pass * 32 + (t >> 3);
      const int cc = (t & 7) * 8;
      *(uint4*)&xt[((size_t)(b * PPX + p0 + pr)) * 256 + c0 + cc] = *(const uint4*)&T[pr][cc];
    }
    return;
  }
  int idx = bid * 256 + t;
  if (idx >= PTOT) return;
  if (idx < POFF1) { wqb[idx] = f2bf(wq[idx]); return; }
  if (idx < POFF2) { const int i = idx - POFF1; wkb[i] = f2bf(wk[i]); return; }
  if (idx < POFF3) { const int i = idx - POFF2; wvb[i] = f2bf(wv[i]); return; }
  if (idx < POFF4) {
    const int i = idx - POFF3;
    bqk[i] = (i < 256) ? bq[i] : bk[i - 256];
    return;
  }
  if (idx < POFF5) {
    const int i = idx - POFF4;               // repack w1, Cin=256
    const int c = i % 256;
    const int rest = i / 256;
    const int o = rest % 256;
    const int tap = rest / 256;
    wr1[i] = f2bf(w1[((size_t)o * 256 + c) * 9 + tap]);
    return;
  }
  if (idx < POFF6) {
    const int i = idx - POFF5;               // repack w2, Cin=512
    const int c = i % 512;
    const int rest = i / 512;
    const int o = rest % 256;
    const int tap = rest / 256;
    wr2[i] = f2bf(w2[((size_t)o * 512 + c) * 9 + tap]);
    return;
  }
  // border clears (uint4 granularity)
  unsigned short* p;
  int C, r;
  if (idx < POFF7) { p = attn_p; C = 256; r = idx - POFF6; }
  else             { p = cat_p;  C = 512; r = idx - POFF7; }
  const int v4 = C >> 3;
  const int perB = 196 * v4;
  const int b = r / perB;
  const int rr = r - b * perB;
  const int pos = rr / v4;
  const int co = (rr - pos * v4) * 8;
  int pp;
  if (pos < 50)        pp = pos;                                   // row 0
  else if (pos < 100)  pp = 2450 + (pos - 50);                     // row 49
  else { const int j = pos - 100; pp = (1 + (j >> 1)) * 50 + (j & 1) * 49; }
  uint4 z; z.x = 0; z.y = 0; z.z = 0; z.w = 0;
  *(uint4*)(p + ((size_t)b * PADIMG + pp) * C + co) = z;
}

// ---------------------------------------------------------------------------
// Generic bf16 MFMA GEMM: O[n][m] = sum_k A[m][k]*B[n][k]
// Tile 128x128, 4 waves (2x2 of 64x64). Round-3 proven schedule.
// EPI: 2 bias on n (V gemm only)
// ---------------------------------------------------------------------------
template<int EPI>
__global__ __launch_bounds__(256) void gemm_nt(
    const unsigned short* __restrict__ A, long Ab,
    const unsigned short* __restrict__ B, long Bb, int K,
    unsigned short* __restrict__ O, long Ob, int ldo,
    const float* __restrict__ bias)
{
  const int t = threadIdx.x;
  const int ln = t & 63;
  const int wid = t >> 6;
  const int wm = (wid & 1) * 64, wn = (wid >> 1) * 64;
  const int lm = ln & 15, lg = ln >> 4;
  const int m0 = blockIdx.x * 128, n0 = blockIdx.y * 128;
  const long bz = blockIdx.z;
  const unsigned short* Ap = A + bz * Ab;
  const unsigned short* Bp = B + bz * Bb;

  __shared__ __align__(16) unsigned short As[128 * 32];
  __shared__ __align__(16) unsigned short Bs[128 * 32];

  const int sR = ln >> 2, sP = ln & 3;
  const int fbase = lm * 32 + (((lg + (lm >> 2)) & 3) * 8);

  f4_t acc[4][4];
  #pragma unroll
  for (int i = 0; i < 4; i++)
    #pragma unroll
    for (int j = 0; j < 4; j++) acc[i][j] = (f4_t){0.f, 0.f, 0.f, 0.f};

  for (int k0 = 0; k0 < K; k0 += 32) {
    __syncthreads();
    #pragma unroll
    for (int i = wid; i < 8; i += 4) {
      const int R = i * 16 + sR;
      const int l = (sP - (R >> 2)) & 3;              // logical chan-group
      gll16(Ap + (size_t)(m0 + R) * K + k0 + l * 8, As + i * 512);
      gll16(Bp + (size_t)(n0 + R) * K + k0 + l * 8, Bs + i * 512);
    }
    __syncthreads();
    short8_t a[4], b[4];
    #pragma unroll
    for (int ti = 0; ti < 4; ti++)
      a[ti] = *(const short8_t*)(As + (wm + ti * 16) * 32 + fbase);
    #pragma unroll
    for (int tj = 0; tj < 4; tj++)
      b[tj] = *(const short8_t*)(Bs + (wn + tj * 16) * 32 + fbase);
    #pragma unroll
    for (int ti = 0; ti < 4; ti++)
      #pragma unroll
      for (int tj = 0; tj < 4; tj++)
        acc[ti][tj] = __builtin_amdgcn_mfma_f32_16x16x32_bf16(
            a[ti], b[tj], acc[ti][tj], 0, 0, 0);
  }

  #pragma unroll
  for (int ti = 0; ti < 4; ti++) {
    const int mb = m0 + wm + ti * 16 + (lg << 2);
    #pragma unroll
    for (int tj = 0; tj < 4; tj++) {
      const int n = n0 + wn + tj * 16 + lm;
      float add0 = 0.f, add1 = 0.f, add2 = 0.f, add3 = 0.f;
      if (EPI == 2) { add0 = add1 = add2 = add3 = bias[n]; }
      uint2 o;
      o.x = pack2(acc[ti][tj][0] + add0, acc[ti][tj][1] + add1);
      o.y = pack2(acc[ti][tj][2] + add2, acc[ti][tj][3] + add3);
      *(uint2*)(O + bz * Ob + (size_t)n * ldo + mb) = o;
    }
  }
}

// ---------------------------------------------------------------------------
// QK^T GEMM, tile 128x128, BK=128: FOUR 32-chan sub-slices staged per barrier
// (round-12 proven recipe extended), 64 MFMA per wave per iteration, 18
// barriers. 64 KB LDS -> 2 blocks/CU (matches current effective occupancy),
// acc stays 4x4. XCD-swizzled block order.
// ---------------------------------------------------------------------------
__global__ __launch_bounds__(256) void gemm_s(
    const unsigned short* __restrict__ A, long Ab,
    const unsigned short* __restrict__ B, long Bb,
    unsigned short* __restrict__ O, long Ob, int ldo)
{
  const int K = 256;
  const int t = threadIdx.x;
  const int ln = t & 63;
  const int wid = t >> 6;
  const int wm = (wid & 1) * 64, wn = (wid >> 1) * 64;
  const int lm = ln & 15, lg = ln >> 4;

  const int lin = swz_lin();
  const int lx = lin % (int)gridDim.x;
  const int rest = lin / (int)gridDim.x;
  const int ly = rest % (int)gridDim.y;
  const int lz = rest / (int)gridDim.y;

  const int m0 = lx * 128, n0 = ly * 128;
  const long bz = lz;
  const unsigned short* Ap = A + bz * Ab;
  const unsigned short* Bp = B + bz * Bb;

  __shared__ __align__(16) unsigned short As[4][128 * 32];
  __shared__ __align__(16) unsigned short Bs[4][128 * 32];

  const int sR = ln >> 2, sP = ln & 3;
  const int fbase = lm * 32 + (((lg + (lm >> 2)) & 3) * 8);

  f4_t acc[4][4];
  #pragma unroll
  for (int i = 0; i < 4; i++)
    #pragma unroll
    for (int j = 0; j < 4; j++) acc[i][j] = (f4_t){0.f, 0.f, 0.f, 0.f};

  for (int k0 = 0; k0 < K; k0 += 128) {
    __syncthreads();
    #pragma unroll
    for (int s = 0; s < 4; s++) {
      #pragma unroll
      for (int i = wid; i < 8; i += 4) {
        const int R = i * 16 + sR;
        const int l = (sP - (R >> 2)) & 3;
        gll16(Ap + (size_t)(m0 + R) * K + k0 + s * 32 + l * 8, &As[s][i * 512]);
        gll16(Bp + (size_t)(n0 + R) * K + k0 + s * 32 + l * 8, &Bs[s][i * 512]);
      }
    }
    __syncthreads();
    #pragma unroll
    for (int s = 0; s < 4; s++) {
      short8_t a[4], b[4];
      #pragma unroll
      for (int ti = 0; ti < 4; ti++)
        a[ti] = *(const short8_t*)(&As[s][(wm + ti * 16) * 32 + fbase]);
      #pragma unroll
      for (int tj = 0; tj < 4; tj++)
        b[tj] = *(const short8_t*)(&Bs[s][(wn + tj * 16) * 32 + fbase]);
      #pragma unroll
      for (int ti = 0; ti < 4; ti++)
        #pragma unroll
        for (int tj = 0; tj < 4; tj++)
          acc[ti][tj] = __builtin_amdgcn_mfma_f32_16x16x32_bf16(
              a[ti], b[tj], acc[ti][tj], 0, 0, 0);
    }
  }

  #pragma unroll
  for (int ti = 0; ti < 4; ti++) {
    const int mb = m0 + wm + ti * 16 + (lg << 2);
    #pragma unroll
    for (int tj = 0; tj < 4; tj++) {
      const int n = n0 + wn + tj * 16 + lm;
      uint2 o;
      o.x = pack2(acc[ti][tj][0], acc[ti][tj][1]);
      o.y = pack2(acc[ti][tj][2], acc[ti][tj][3]);
      *(uint2*)(O + bz * Ob + (size_t)n * ldo + mb) = o;
    }
  }
}

// ---------------------------------------------------------------------------
// Merged Q+K GEMM (standalone clone of gemm_nt): A = wqb||wkb [512][256],
// B = xt. Rows 0..255 -> qt, 256..511 -> kt (= qt + NTOT).
// ---------------------------------------------------------------------------
__global__ __launch_bounds__(256) void gemm_qk2(
    const unsigned short* __restrict__ A,
    const unsigned short* __restrict__ B, long Bb,
    unsigned short* __restrict__ Oq,
    const float* __restrict__ bias)
{
  const int t = threadIdx.x;
  const int ln = t & 63;
  const int wid = t >> 6;
  const int wm = (wid & 1) * 64, wn = (wid >> 1) * 64;
  const int lm = ln & 15, lg = ln >> 4;
  const int m0 = blockIdx.x * 128, n0 = blockIdx.y * 128;
  const long bz = blockIdx.z;
  const int K = 256;
  const unsigned short* Ap = A;
  const unsigned short* Bp = B + bz * Bb;

  __shared__ __align__(16) unsigned short As[128 * 32];
  __shared__ __align__(16) unsigned short Bs[128 * 32];

  const int sR = ln >> 2, sP = ln & 3;
  const int fbase = lm * 32 + (((lg + (lm >> 2)) & 3) * 8);

  f4_t acc[4][4];
  #pragma unroll
  for (int i = 0; i < 4; i++)
    #pragma unroll
    for (int j = 0; j < 4; j++) acc[i][j] = (f4_t){0.f, 0.f, 0.f, 0.f};

  for (int k0 = 0; k0 < K; k0 += 32) {
    __syncthreads();
    #pragma unroll
    for (int i = wid; i < 8; i += 4) {
      const int R = i * 16 + sR;
      const int l = (sP - (R >> 2)) & 3;
      gll16(Ap + (size_t)(m0 + R) * K + k0 + l * 8, As + i * 512);
      gll16(Bp + (size_t)(n0 + R) * K + k0 + l * 8, Bs + i * 512);
    }
    __syncthreads();
    short8_t a[4], b[4];
    #pragma unroll
    for (int ti = 0; ti < 4; ti++)
      a[ti] = *(const short8_t*)(As + (wm + ti * 16) * 32 + fbase);
    #pragma unroll
    for (int tj = 0; tj < 4; tj++)
      b[tj] = *(const short8_t*)(Bs + (wn + tj * 16) * 32 + fbase);
    #pragma unroll
    for (int ti = 0; ti < 4; ti++)
      #pragma unroll
      for (int tj = 0; tj < 4; tj++)
        acc[ti][tj] = __builtin_amdgcn_mfma_f32_16x16x32_bf16(
            a[ti], b[tj], acc[ti][tj], 0, 0, 0);
  }

  #pragma unroll
  for (int ti = 0; ti < 4; ti++) {
    const int mb = m0 + wm + ti * 16 + (lg << 2);     // 0..511, wave-uniform split
    const size_t obase = (mb >= 256 ? (size_t)NTOT : 0) + (size_t)bz * CPb;
    const int mc = mb & 255;
    #pragma unroll
    for (int tj = 0; tj < 4; tj++) {
      const int n = n0 + wn + tj * 16 + lm;
      uint2 o;
      o.x = pack2(acc[ti][tj][0] + bias[mb],     acc[ti][tj][1] + bias[mb + 1]);
      o.y = pack2(acc[ti][tj][2] + bias[mb + 2], acc[ti][tj][3] + bias[mb + 3]);
      *(uint2*)(Oq + obase + (size_t)n * 256 + mc) = o;
    }
  }
}

// ---------------------------------------------------------------------------
// PV GEMM: tile 128(M=chan) x 64(N=pixel), 4 waves 2x2 (each 64x32, acc 4x2).
// BK=32, 12 KB LDS, XCD-swizzled (St x-pair shares one XCD's L2).
// Epilogue: out = delta*acc + x (bf16 from xt, coalesced) -> attn_p [pos][256].
// ---------------------------------------------------------------------------
__global__ __launch_bounds__(256) void gemm_pv64(
    const unsigned short* __restrict__ A, long Ab,   // vbuf [c][i]
    const unsigned short* __restrict__ B, long Bb,   // St weights [j][i]
    int K,
    unsigned short* __restrict__ O,                  // attn_p
    const unsigned short* __restrict__ X,            // xt [b][p][c] bf16
    const float* __restrict__ delta, int bstart)
{
  const int t = threadIdx.x;
  const int ln = t & 63;
  const int wid = t >> 6;
  const int wm = (wid & 1) * 64, wn = (wid >> 1) * 32;
  const int lm = ln & 15, lg = ln >> 4;

  const int lin = swz_lin();
  const int lx = lin % (int)gridDim.x;
  const int rest = lin / (int)gridDim.x;
  const int ly = rest % (int)gridDim.y;
  const int lz = rest / (int)gridDim.y;

  const int m0 = lx * 128, n0 = ly * 64;
  const long bz = lz;
  const int b = bstart + (int)bz;
  const unsigned short* Ap = A + bz * Ab;
  const unsigned short* Bp = B + bz * Bb;

  __shared__ __align__(16) unsigned short As[128 * 32];
  __shared__ __align__(16) unsigned short Bs[64 * 32];

  const int sR = ln >> 2, sP = ln & 3;
  const int fbase = lm * 32 + (((lg + (lm >> 2)) & 3) * 8);

  f4_t acc[4][2];
  #pragma unroll
  for (int i = 0; i < 4; i++)
    #pragma unroll
    for (int j = 0; j < 2; j++) acc[i][j] = (f4_t){0.f, 0.f, 0.f, 0.f};

  for (int k0 = 0; k0 < K; k0 += 32) {
    __syncthreads();
    #pragma unroll
    for (int i = wid; i < 8; i += 4) {
      const int R = i * 16 + sR;
      const int l = (sP - (R >> 2)) & 3;
      gll16(Ap + (size_t)(m0 + R) * K + k0 + l * 8, As + i * 512);
    }
    {
      const int R = wid * 16 + sR;                    // 4 chunks, 1 per wave
      const int l = (sP - (R >> 2)) & 3;
      gll16(Bp + (size_t)(n0 + R) * K + k0 + l * 8, Bs + wid * 512);
    }
    __syncthreads();
    short8_t a[4], b8[2];
    #pragma unroll
    for (int ti = 0; ti < 4; ti++)
      a[ti] = *(const short8_t*)(As + (wm + ti * 16) * 32 + fbase);
    #pragma unroll
    for (int tj = 0; tj < 2; tj++)
      b8[tj] = *(const short8_t*)(Bs + (wn + tj * 16) * 32 + fbase);
    #pragma unroll
    for (int ti = 0; ti < 4; ti++)
      #pragma unroll
      for (int tj = 0; tj < 2; tj++)
        acc[ti][tj] = __builtin_amdgcn_mfma_f32_16x16x32_bf16(
            a[ti], b8[tj], acc[ti][tj], 0, 0, 0);
  }

  const float d0 = delta[0];
  #pragma unroll
  for (int ti = 0; ti < 4; ti++) {
    const int mb = m0 + wm + ti * 16 + (lg << 2);     // channel c
    #pragma unroll
    for (int tj = 0; tj < 2; tj++) {
      const int n = n0 + wn + tj * 16 + lm;            // pixel j
      const int y = n / 48, x = n - (n / 48) * 48;
      const size_t pp = (size_t)(y + 1) * 50 + (x + 1);
      const uint2 xv = *(const uint2*)(X + ((size_t)b * PPX + n) * 256 + mb);
      float fr[4];
      fr[0] = bf2f((unsigned short)(xv.x & 0xffffu));
      fr[1] = bf2f((unsigned short)(xv.x >> 16));
      fr[2] = bf2f((unsigned short)(xv.y & 0xffffu));
      fr[3] = bf2f((unsigned short)(xv.y >> 16));
      float vr[4];
      #pragma unroll
      for (int r = 0; r < 4; r++)
        vr[r] = d0 * acc[ti][tj][r] + fr[r];
      uint2 o;
      o.x = pack2(vr[0], vr[1]);
      o.y = pack2(vr[2], vr[3]);
      *(uint2*)(O + ((size_t)b * PADIMG + pp) * 256 + mb) = o;
    }
  }
}

// ---------------------------------------------------------------------------
// Row softmax of St IN PLACE: row j: W[i] = exp(s-mx)/sum  (bf16 out)
// ---------------------------------------------------------------------------
__global__ __launch_bounds__(256) void rowstats(
    unsigned short* __restrict__ St, long sstride)
{
  const int j = blockIdx.x, bb = blockIdx.y;
  unsigned short* row = St + (long)bb * sstride + (size_t)j * PPX;
  const int t = threadIdx.x;

  float v[16];
  int nv = 0;
  float m = -1e30f;
  for (int ch = t; ch < 288; ch += 256) {
    const uint4 d = *(const uint4*)(row + ch * 8);
    const unsigned int* dp = (const unsigned int*)&d;
    #pragma unroll
    for (int q = 0; q < 4; q++) {
      v[nv]     = bf2f((unsigned short)(dp[q] & 0xffffu));
      v[nv + 1] = bf2f((unsigned short)(dp[q] >> 16));
      m = fmaxf(m, fmaxf(v[nv], v[nv + 1]));
      nv += 2;
    }
  }
  #pragma unroll
  for (int off = 32; off > 0; off >>= 1)
    m = fmaxf(m, __shfl_xor(m, off));
  __shared__ float red[8];
  if ((t & 63) == 0) red[t >> 6] = m;
  __syncthreads();
  m = fmaxf(fmaxf(red[0], red[1]), fmaxf(red[2], red[3]));

  float sum = 0.f;
  for (int u = 0; u < nv; u++) { v[u] = __expf(v[u] - m); sum += v[u]; }
  #pragma unroll
  for (int off = 32; off > 0; off >>= 1)
    sum += __shfl_xor(sum, off);
  if ((t & 63) == 0) red[4 + (t >> 6)] = sum;
  __syncthreads();
  const float inv = 1.f / (red[4] + red[5] + red[6] + red[7]);

  int u = 0;
  for (int ch = t; ch < 288; ch += 256) {
    unsigned int res[4];
    #pragma unroll
    for (int q = 0; q < 4; q++) {
      res[q] = pack2(v[u] * inv, v[u + 1] * inv);
      u += 2;
    }
    *(uint4*)(row + ch * 8) = *(const uint4*)res;
  }
}

// ---------------------------------------------------------------------------
// Conv3x3 + BN + ReLU, MFMA bf16, [pos][chan] activations, async LDS staging.
// 256 thr (4 waves), tile 32 Cout x 192 px. Grid = 768 blocks = 3/CU.
// FUSE_POOL (conv1): epilogue computes gate=sigmoid(bf16(act1)) in-register
// and writes pooled xt (max & avg) * gate directly to cat_p [pos][512].
// ---------------------------------------------------------------------------
template<bool FUSE_POOL>
__global__ __launch_bounds__(256) void conv_mfma(
    const unsigned short* __restrict__ act_p, int Cin,
    const unsigned short* __restrict__ wr,
    const float* __restrict__ gamma, const float* __restrict__ beta,
    const float* __restrict__ mean,  const float* __restrict__ var,
    void* __restrict__ outv, const unsigned short* __restrict__ xtp)
{
  const int t  = threadIdx.x;
  const int wv = t >> 6;          // wave 0..3 -> 48-px chunk
  const int ln = t & 63;
  const int lm = ln & 15;
  const int lg = ln >> 4;

  const int bx = blockIdx.x;      // 96 = 8 images * 12 pixel-tiles (192 px)
  const int bb = bx / 12;
  const int p0 = (bx % 12) * 192;
  const int m0 = blockIdx.y * 32; // 8 m-tiles of 32 Cout

  __shared__ __align__(16) unsigned short As[9 * 32 * 32]; // [tap][m][c] 18.4 KB
  __shared__ __align__(16) unsigned short Bs[304 * 32];    // [pos][c]    19.5 KB

  const int qbase = p0 + 2 * (p0 / 48);    // q(p0) - 51
  int qoff[3];
  #pragma unroll
  for (int tj = 0; tj < 3; tj++) {
    const int p = p0 + wv * 48 + tj * 16 + lm;
    qoff[tj] = (p - p0) + 2 * (p / 48 - p0 / 48) + 51;
  }

  const int sR = ln >> 2, sP = ln & 3;
  const int sl = (sP - (sR >> 2)) & 3;
  const int abase = lm * 32 + (((lg + (lm >> 2)) & 3) * 8);

  const unsigned short* gb = act_p + (size_t)bb * PADIMG * Cin + sl * 8;

  f4_t acc[2][3];
  #pragma unroll
  for (int i = 0; i < 2; i++)
    #pragma unroll
    for (int j = 0; j < 3; j++) acc[i][j] = (f4_t){0.f, 0.f, 0.f, 0.f};

  for (int c0 = 0; c0 < Cin; c0 += 32) {
    __syncthreads();
    for (int i = wv; i < 18; i += 4) {
      const int R = i * 16 + sR;                          // 0..287
      const int tap = R >> 5, mr = R & 31;
      const int l = (sP - (R >> 2)) & 3;
      gll16(wr + ((size_t)(tap * 256 + m0 + mr)) * Cin + c0 + l * 8, As + i * 512);
    }
    for (int i = wv; i < 19; i += 4) {
      const int R = i * 16 + sR;                          // 0..303
      int Rg = qbase + R;
      if (Rg > PADIMG - 1) Rg = PADIMG - 1;
      gll16(gb + (size_t)Rg * Cin + c0, Bs + i * 512);
    }
    __syncthreads();
    #pragma unroll
    for (int ky = 0; ky < 3; ky++) {
      #pragma unroll
      for (int kx = 0; kx < 3; kx++) {
        const int off = (ky - 1) * 50 + (kx - 1);
        const int tap = ky * 3 + kx;
        short8_t a[2], b[3];
        #pragma unroll
        for (int ti = 0; ti < 2; ti++)
          a[ti] = *(const short8_t*)(As + tap * 1024 + ti * 512 + abase);
        #pragma unroll
        for (int tj = 0; tj < 3; tj++) {
          const int R = qoff[tj] + off;
          const int slot = (lg + (R >> 2)) & 3;
          b[tj] = *(const short8_t*)(Bs + R * 32 + slot * 8);
        }
        #pragma unroll
        for (int ti = 0; ti < 2; ti++)
          #pragma unroll
          for (int tj = 0; tj < 3; tj++)
            acc[ti][tj] = __builtin_amdgcn_mfma_f32_16x16x32_bf16(
                a[ti], b[tj], acc[ti][tj], 0, 0, 0);
      }
    }
  }

  // ---- epilogue: BN + ReLU (+ fused pool/gate/cat for conv1) ----
  #pragma unroll
  for (int ti = 0; ti < 2; ti++) {
    const int m = m0 + ti * 16 + (lg << 2);
    float inv[4], add[4];
    #pragma unroll
    for (int r = 0; r < 4; r++) {
      inv[r] = gamma[m + r] * rsqrtf(var[m + r] + 1e-5f);
      add[r] = beta[m + r] - mean[m + r] * inv[r];
    }
    #pragma unroll
    for (int tj = 0; tj < 3; tj++) {
      const int p = p0 + wv * 48 + tj * 16 + lm;
      float vr[4];
      #pragma unroll
      for (int r = 0; r < 4; r++)
        vr[r] = relu_(acc[ti][tj][r] * inv[r] + add[r]);
      if (FUSE_POOL) {
        const int y = p / 48, x = p - y * 48;
        // gate from bf16-rounded act1 (matches old act1b store/load)
        float gt[4];
        #pragma unroll
        for (int r = 0; r < 4; r++) {
          const float a1 = bf2f(f2bf(vr[r]));
          gt[r] = 1.f / (1.f + __expf(-a1));
        }
        // pool xt 3x3 (dy-major, dx-minor; identical accumulation order)
        float s[4], mx[4];
        #pragma unroll
        for (int r = 0; r < 4; r++) { s[r] = 0.f; mx[r] = -1e30f; }
        #pragma unroll
        for (int dy = -1; dy <= 1; dy++) {
          const int yy = y + dy;
          if (yy < 0 || yy >= 48) continue;
          #pragma unroll
          for (int dx = -1; dx <= 1; dx++) {
            const int xx = x + dx;
            if (xx < 0 || xx >= 48) continue;
            const uint2 xv = *(const uint2*)(xtp +
                ((size_t)(bb * PPX + yy * 48 + xx)) * 256 + m);
            float f0 = bf2f((unsigned short)(xv.x & 0xffffu));
            float f1 = bf2f((unsigned short)(xv.x >> 16));
            float f2 = bf2f((unsigned short)(xv.y & 0xffffu));
            float f3 = bf2f((unsigned short)(xv.y >> 16));
            s[0] += f0; s[1] += f1; s[2] += f2; s[3] += f3;
            mx[0] = fmaxf(mx[0], f0); mx[1] = fmaxf(mx[1], f1);
            mx[2] = fmaxf(mx[2], f2); mx[3] = fmaxf(mx[3], f3);
          }
        }
        const size_t pp = (size_t)(y + 1) * 50 + (x + 1);
        unsigned short* crow = (unsigned short*)outv +
            ((size_t)bb * PADIMG + pp) * 512 + m;
        uint2 om, oa;
        om.x = pack2(mx[0] * gt[0], mx[1] * gt[1]);
        om.y = pack2(mx[2] * gt[2], mx[3] * gt[3]);
        oa.x = pack2(s[0] * (1.f / 9.f) * gt[0], s[1] * (1.f / 9.f) * gt[1]);
        oa.y = pack2(s[2] * (1.f / 9.f) * gt[2], s[3] * (1.f / 9.f) * gt[3]);
        *(uint2*)crow = om;
        *(uint2*)(crow + 256) = oa;
      } else {
        #pragma unroll
        for (int r = 0; r < 4; r++)
          ((float*)outv)[((size_t)(bb * 256 + m + r)) * PPX + p] = vr[r];
      }
    }
  }
}

// ---------------------------------------------------------------------------
extern "C" void kernel_launch(void* const* d_in, const int* in_sizes, int n_in,
                              void* d_out, int out_size, void* d_ws, size_t ws_size,
                              hipStream_t stream)
{
  const float* ftr  = (const float*)d_in[0];
  const float* wq   = (const float*)d_in[1];
  const float* bq   = (const float*)d_in[2];
  const float* wk   = (const float*)d_in[3];
  const float* bk   = (const float*)d_in[4];
  const float* wv   = (const float*)d_in[5];
  const float* bv   = (const float*)d_in[6];
  const float* delta= (const float*)d_in[7];
  const float* w1   = (const float*)d_in[8];
  const float* g1   = (const float*)d_in[9];
  const float* b1   = (const float*)d_in[10];
  const float* m1   = (const float*)d_in[11];
  const float* v1   = (const float*)d_in[12];
  const float* w2   = (const float*)d_in[13];
  const float* g2   = (const float*)d_in[14];
  const float* b2   = (const float*)d_in[15];
  const float* m2   = (const float*)d_in[16];
  const float* v2   = (const float*)d_in[17];
  float* out = (float*)d_out;

  // ---- workspace layout (shorts) ----
  const size_t XT = (size_t)NTOT;
  unsigned short* base = (unsigned short*)d_ws;
  unsigned short* xt   = base;
  unsigned short* qt   = xt  + XT;
  unsigned short* kt   = qt  + XT;        // MUST stay qt + NTOT (gemm_qk2 relies on it)
  unsigned short* vbuf = kt  + XT;
  unsigned short* wqb  = vbuf + XT;
  unsigned short* wkb  = wqb + 65536;     // MUST stay wqb + 65536 (contiguous A)
  unsigned short* wvb  = wkb + 65536;
  unsigned short* wr1  = wvb + 65536;
  unsigned short* wr2  = wr1 + (size_t)9 * 256 * 256;
  unsigned short* attn_p = wr2 + (size_t)9 * 256 * 512;        // [b][2500][256]
  unsigned short* act1b  = attn_p + (size_t)NB * PADIMG * 256; // bqk overlay region
  unsigned short* cat_p  = act1b + XT;                         // [b][2500][512]
  unsigned short* St     = cat_p + (size_t)NB * PADIMG * 512;

  // bqk (512 floats) overlays act1b region (otherwise unused now)
  float* bqk = (float*)act1b;

  const size_t head_bytes = (size_t)((char*)St - (char*)base);
  const bool modeA = ws_size >= head_bytes + (size_t)NB * PSQ * 2;

  // ---- ONE merged prep launch: casts+biascat+repacks+borders+transpose ----
  prep<<<dim3(PB + TB), 256, 0, stream>>>(
      wq, wk, wv, bq, bk, w1, w2, ftr,
      wqb, wkb, wvb, bqk, wr1, wr2, attn_p, cat_p, xt);

  // ---- QKV: merged Q+K (576 blocks), V separate ----
  gemm_qk2<<<dim3(4, 18, 8), 256, 0, stream>>>(wqb, xt, (long)CPb, qt, bqk);
  gemm_nt<2><<<dim3(18, 2, 8), 256, 0, stream>>>(
      xt, (long)CPb, wvb, 0L, 256, vbuf, (long)CPb, PPX, bv);

  if (modeA) {
    gemm_s<<<dim3(18, 18, 8), 256, 0, stream>>>(
        qt, (long)CPb, kt, (long)CPb, St, (long)PSQ, PPX);
    rowstats<<<dim3(PPX, 8), 256, 0, stream>>>(St, (long)PSQ);
    gemm_pv64<<<dim3(2, 36, 8), 256, 0, stream>>>(
        vbuf, (long)CPb, St, (long)PSQ, PPX, attn_p, xt, delta, 0);
  } else {
    for (int b = 0; b < NB; b++) {
      gemm_s<<<dim3(18, 18, 1), 256, 0, stream>>>(
          qt + (size_t)b * CPb, 0L, kt + (size_t)b * CPb, 0L, St, 0L, PPX);
      rowstats<<<dim3(PPX, 1), 256, 0, stream>>>(St, 0L);
      gemm_pv64<<<dim3(2, 36, 1), 256, 0, stream>>>(
          vbuf + (size_t)b * CPb, 0L, St, 0L, PPX, attn_p, xt, delta, b);
    }
  }

  // ---- conv1 + BN + ReLU + FUSED pool/gate/cat -> cat_p [pos][512] ----
  conv_mfma<true><<<dim3(96, 8), 256, 0, stream>>>(
      attn_p, 256, wr1, g1, b1, m1, v1, (void*)cat_p, xt);

  // ---- conv2 + BN + ReLU -> fp32 out ----
  conv_mfma<false><<<dim3(96, 8), 256, 0, stream>>>(
      cat_p, 512, wr2, g2, b2, m2, v2, (void*)out, nullptr);
}